// Round 3
// baseline (7531.790 us; speedup 1.0000x reference)
//
#include <hip/hip_runtime.h>
#include <math.h>

#define NORI 20
#define NPTS 160
#define CDIM 128
#define TWO_PI_OVER_O (6.28318530717958647692f / 20.0f)
#define SA 132            // s_act row stride (floats)
#define SW 132            // s_w row stride (floats)
#define NT 64             // n-rows per tile

__device__ __forceinline__ float gelu_exact(float x) {
    return 0.5f * x * (1.0f + erff(x * 0.70710678118654752440f));
}
__device__ __forceinline__ float4 ld4(const float* p) { return *(const float4*)p; }

#define FMA4(d, s, v) { d.x += (s)*(v).x; d.y += (s)*(v).y; d.z += (s)*(v).z; d.w += (s)*(v).w; }
#define MUL4ACC(d, a, b) { d.x += (a).x*(b).x; d.y += (a).y*(b).y; d.z += (a).z*(b).z; d.w += (a).w*(b).w; }
#define GELU4B(d, bias) { d.x = gelu_exact(d.x + (bias).x); d.y = gelu_exact(d.y + (bias).y); \
                          d.z = gelu_exact(d.z + (bias).z); d.w = gelu_exact(d.w + (bias).w); }

// ---------------------------------------------------------------------------
// fk[l,p,o,c]
// ---------------------------------------------------------------------------
__global__ __launch_bounds__(128) void fk_kernel(
    const float* __restrict__ fw1, const float* __restrict__ fb1,
    const float* __restrict__ fw2, const float* __restrict__ fb2,
    const float* __restrict__ fiber_w, float* __restrict__ fk)
{
    __shared__ float s_u[CDIM];
    __shared__ float s_z[CDIM];
    int bid = blockIdx.x;
    int l = bid / 400;
    int rem = bid % 400;
    int p = rem / 20, o = rem % 20;
    int j = threadIdx.x;

    float t = cosf(TWO_PI_OVER_O * (float)(p - o));
    float f1 = t * t, f2 = f1 * t;

    float u = gelu_exact(t * fw1[j] + f1 * fw1[CDIM + j] + f2 * fw1[2 * CDIM + j] + fb1[j]);
    s_u[j] = u;
    __syncthreads();

    float z0 = 0.f, z1 = 0.f, z2 = 0.f, z3 = 0.f;
    for (int i = 0; i < CDIM; i += 4) {
        z0 += s_u[i    ] * fw2[(i    ) * CDIM + j];
        z1 += s_u[i + 1] * fw2[(i + 1) * CDIM + j];
        z2 += s_u[i + 2] * fw2[(i + 2) * CDIM + j];
        z3 += s_u[i + 3] * fw2[(i + 3) * CDIM + j];
    }
    float z = gelu_exact(((z0 + z1) + (z2 + z3)) + fb2[j]);
    s_z[j] = z;
    __syncthreads();

    const float* fw = fiber_w + l * CDIM * CDIM;
    float a0 = 0.f, a1 = 0.f, a2 = 0.f, a3 = 0.f;
    for (int i = 0; i < CDIM; i += 4) {
        a0 += s_z[i    ] * fw[(i    ) * CDIM + j];
        a1 += s_z[i + 1] * fw[(i + 1) * CDIM + j];
        a2 += s_z[i + 2] * fw[(i + 2) * CDIM + j];
        a3 += s_z[i + 3] * fw[(i + 3) * CDIM + j];
    }
    fk[bid * CDIM + j] = (a0 + a1) + (a2 + a3);
}

// ---------------------------------------------------------------------------
// h0
// ---------------------------------------------------------------------------
__global__ __launch_bounds__(128) void h0_kernel(
    const float* __restrict__ x, const float* __restrict__ emb_w,
    float* __restrict__ h)
{
    int row = blockIdx.x;
    int j = threadIdx.x;
    const float* xr = x + row * 16;
    float acc = 0.f;
#pragma unroll
    for (int i = 0; i < 16; ++i) acc += xr[i] * emb_w[i * CDIM + j];
    h[row * CDIM + j] = acc;
}

// ---------------------------------------------------------------------------
// register-tiled 64x128 GEMM over k=128 with LDS-staged weight panels
// ---------------------------------------------------------------------------
__device__ __forceinline__ void st_panel(float* dst, int f, float4 v) {
    int row = f >> 7, col = f & 127;
    *(float4*)&dst[row * SW + col] = v;
}

#define GSTEP(Q, C) { \
    float4 wa = ld4(wr + (Q) * SW); \
    float4 wv = ld4(wr + (Q) * SW + 4); \
    _Pragma("unroll") \
    for (int r = 0; r < 4; ++r) if (r < nr) { \
        float s_ = u4[r].C; \
        FMA4(acc[r][0], s_, wa); \
        FMA4(acc[r][1], s_, wv); } }

__device__ __forceinline__ void gemm_tile(
    const float* sact, float* sw0, const float* __restrict__ W,
    int tid, int rg, int c0, int nr, float4 acc[4][2])
{
    const int f0 = tid * 4, f1 = f0 + 1024, f2 = f0 + 2048, f3 = f0 + 3072;
    st_panel(sw0, f0, ld4(W + f0));
    st_panel(sw0, f1, ld4(W + f1));
    st_panel(sw0, f2, ld4(W + f2));
    st_panel(sw0, f3, ld4(W + f3));
    __syncthreads();
    int buf = 0;
    for (int pnl = 0; pnl < 4; ++pnl) {
        float4 t0, t1, t2, t3;
        if (pnl < 3) {
            const float* Wp = W + (pnl + 1) * 4096;
            t0 = ld4(Wp + f0); t1 = ld4(Wp + f1); t2 = ld4(Wp + f2); t3 = ld4(Wp + f3);
        }
        const float* wbase = sw0 + buf * 32 * SW;
        const float* abase = sact + pnl * 32;
#pragma unroll
        for (int i4 = 0; i4 < 8; ++i4) {
            float4 u4[4];
#pragma unroll
            for (int r = 0; r < 4; ++r)
                if (r < nr) u4[r] = ld4(abase + (rg + 16 * r) * SA + i4 * 4);
            const float* wr = wbase + i4 * 4 * SW + c0;
            GSTEP(0, x) GSTEP(1, y) GSTEP(2, z) GSTEP(3, w)
        }
        if (pnl < 3) {
            float* dst = sw0 + (buf ^ 1) * 32 * SW;
            st_panel(dst, f0, t0); st_panel(dst, f1, t1);
            st_panel(dst, f2, t2); st_panel(dst, f3, t3);
        }
        __syncthreads();
        buf ^= 1;
    }
}

// ---------------------------------------------------------------------------
// x1[m,o,c] = sum_n (gelu(gelu(poly@bw1+bb1)@bw2+bb2) @ kw)[n,c] * h[n,o,c]
// one block per (m,o), 256 threads, 64-row tiles, 4x8 micro-tiles
// rg = tid&15 (row group), cg = tid>>4 (col group) -> weight reads are
// 4-unique-address + 16-way broadcast per wave = conflict-free.
// ---------------------------------------------------------------------------
__global__ __launch_bounds__(256, 2) void x1_kernel(
    const float* __restrict__ pos, const float* __restrict__ h,
    const float* __restrict__ bw1, const float* __restrict__ bb1,
    const float* __restrict__ bw2, const float* __restrict__ bb2,
    const float* __restrict__ kw, float* __restrict__ x1)
{
    __shared__ float s_act[NT * SA];        // 33792 B
    __shared__ float s_w[2 * 32 * SW];      // 33792 B
    __shared__ float s_bw1[14 * SW];        // 7392 B
    __shared__ float s_bb1[CDIM];
    __shared__ float s_bb2[CDIM];

    const int tid = threadIdx.x;
    const int rg = tid & 15;        // row group
    const int cg = tid >> 4;        // col group (8 cols)
    const int c0 = cg << 3;

    for (int e = tid; e < 14 * 128; e += 256) {
        int row = e >> 7, col = e & 127;
        s_bw1[row * SW + col] = bw1[e];
    }
    if (tid < 128) {
        s_bb1[tid] = bb1[tid];
        s_bb2[tid] = bb2[tid];
    }

    const int m = blockIdx.x / NORI;
    const int o = blockIdx.x % NORI;
    const float th = TWO_PI_OVER_O * (float)o;
    const float ox = cosf(th), oy = sinf(th);
    const float pmx = pos[2 * m], pmy = pos[2 * m + 1];

    float4 xa = {0.f, 0.f, 0.f, 0.f}, xb = {0.f, 0.f, 0.f, 0.f};
    __syncthreads();

    for (int t = 0; t < 3; ++t) {
        const int n0 = t * NT;
        const int nvalid = (t == 2) ? (NPTS - 2 * NT) : NT;   // 64,64,32
        const int nr = nvalid >> 4;                           // 4,4,2

        // ---- phase U: u = gelu(poly @ bw1 + bb1) -> s_act
#pragma unroll
        for (int r = 0; r < 4; ++r) if (r < nr) {
            int n = n0 + rg + 16 * r;
            float rx = pos[2 * n] - pmx, ry = pos[2 * n + 1] - pmy;
            float a = rx * ox + ry * oy;
            float b = sqrtf(rx * rx + ry * ry) * fabsf(1.0f - a);
            float a2 = a * a, ab = a * b, b2 = b * b;
            float a3 = a2 * a, a2b = a2 * b, ab2 = ab * b, b3 = b2 * b;
            float pv[14] = {a, b, a2, ab, ab, b2, a3, a2b, a2b, ab2, a2b, ab2, ab2, b3};
            float4 ua = {0.f,0.f,0.f,0.f}, ub = {0.f,0.f,0.f,0.f};
#pragma unroll
            for (int i = 0; i < 14; ++i) {
                float4 wa = ld4(&s_bw1[i * SW + c0]);
                float4 wv = ld4(&s_bw1[i * SW + c0 + 4]);
                FMA4(ua, pv[i], wa);
                FMA4(ub, pv[i], wv);
            }
            float4 ba = ld4(&s_bb1[c0]), bbv = ld4(&s_bb1[c0 + 4]);
            GELU4B(ua, ba); GELU4B(ub, bbv);
            *(float4*)&s_act[(rg + 16 * r) * SA + c0] = ua;
            *(float4*)&s_act[(rg + 16 * r) * SA + c0 + 4] = ub;
        }
        __syncthreads();

        // ---- z = gelu(u @ bw2 + bb2)
        float4 acc[4][2];
#pragma unroll
        for (int r = 0; r < 4; ++r) { acc[r][0] = {0.f,0.f,0.f,0.f}; acc[r][1] = {0.f,0.f,0.f,0.f}; }
        gemm_tile(s_act, s_w, bw2, tid, rg, c0, nr, acc);

        float4 zba = ld4(&s_bb2[c0]), zbb = ld4(&s_bb2[c0 + 4]);
#pragma unroll
        for (int r = 0; r < 4; ++r) if (r < nr) {
            float4 za = acc[r][0], zb = acc[r][1];
            GELU4B(za, zba); GELU4B(zb, zbb);
            *(float4*)&s_act[(rg + 16 * r) * SA + c0] = za;
            *(float4*)&s_act[(rg + 16 * r) * SA + c0 + 4] = zb;
        }
        __syncthreads();

        // ---- kern = z @ kw ; x1 partial += kern * h
        float4 kacc[4][2];
#pragma unroll
        for (int r = 0; r < 4; ++r) { kacc[r][0] = {0.f,0.f,0.f,0.f}; kacc[r][1] = {0.f,0.f,0.f,0.f}; }
        gemm_tile(s_act, s_w, kw, tid, rg, c0, nr, kacc);

#pragma unroll
        for (int r = 0; r < 4; ++r) if (r < nr) {
            int n = n0 + rg + 16 * r;
            const float* hp = h + (n * NORI + o) * CDIM + c0;
            float4 ha = ld4(hp), hbv = ld4(hp + 4);
            MUL4ACC(xa, kacc[r][0], ha);
            MUL4ACC(xb, kacc[r][1], hbv);
        }
    }

    // ---- reduce the 16 row-group partials per column
    __syncthreads();
    *(float4*)&s_act[rg * SA + c0] = xa;
    *(float4*)&s_act[rg * SA + c0 + 4] = xb;
    __syncthreads();
    if (tid < 128) {
        float s = 0.f;
#pragma unroll
        for (int g = 0; g < 16; ++g) s += s_act[g * SA + tid];
        x1[(m * NORI + o) * CDIM + tid] = s;
    }
}

// ---------------------------------------------------------------------------
// fiber conv + LN + MLP + residual: 4 p-rows per block, grid = 160*5
// ---------------------------------------------------------------------------
__global__ __launch_bounds__(128) void mlp_kernel(
    const float* __restrict__ x1, const float* __restrict__ fk_l,
    const float* __restrict__ conv_b, const float* __restrict__ ln_g,
    const float* __restrict__ ln_b,
    const float* __restrict__ w1, const float* __restrict__ b1,
    const float* __restrict__ w2, const float* __restrict__ b2,
    float* __restrict__ h)
{
    __shared__ float s_xn[4][132];
    __shared__ float s_mid[4][520];
    __shared__ float s_s1[4][2], s_sq[4][2];

    const int c = threadIdx.x;
    const int m = blockIdx.x / 5, pg = blockIdx.x % 5;
    const int lane = c & 63, wid = c >> 6;

    float x1v[NORI];
#pragma unroll
    for (int o = 0; o < NORI; ++o) x1v[o] = x1[(m * NORI + o) * CDIM + c];

    float x2v[4];
#pragma unroll
    for (int rr = 0; rr < 4; ++rr) {
        int p = pg * 4 + rr;
        float x2 = 0.f;
#pragma unroll
        for (int o = 0; o < NORI; ++o) x2 += x1v[o] * fk_l[(p * NORI + o) * CDIM + c];
        x2 = x2 * (1.0f / 128.0f) + conv_b[c];
        x2v[rr] = x2;
        float s1 = x2, sq = x2 * x2;
        for (int off = 32; off; off >>= 1) {
            s1 += __shfl_down(s1, off, 64);
            sq += __shfl_down(sq, off, 64);
        }
        if (lane == 0) { s_s1[rr][wid] = s1; s_sq[rr][wid] = sq; }
    }
    __syncthreads();
#pragma unroll
    for (int rr = 0; rr < 4; ++rr) {
        float mu  = (s_s1[rr][0] + s_s1[rr][1]) * (1.0f / 128.0f);
        float var = (s_sq[rr][0] + s_sq[rr][1]) * (1.0f / 128.0f) - mu * mu;
        float xn = (x2v[rr] - mu) * rsqrtf(var + 1e-5f) * ln_g[c] + ln_b[c];
        s_xn[rr][c] = xn;
    }
    __syncthreads();

#pragma unroll
    for (int kq = 0; kq < 4; ++kq) {
        int k = kq * CDIM + c;
        float b = b1[k];
        float ac0 = b, ac1 = b, ac2 = b, ac3 = b;
        for (int i = 0; i < CDIM; ++i) {
            float w = w1[i * 512 + k];
            ac0 += s_xn[0][i] * w;
            ac1 += s_xn[1][i] * w;
            ac2 += s_xn[2][i] * w;
            ac3 += s_xn[3][i] * w;
        }
        s_mid[0][k] = gelu_exact(ac0);
        s_mid[1][k] = gelu_exact(ac1);
        s_mid[2][k] = gelu_exact(ac2);
        s_mid[3][k] = gelu_exact(ac3);
    }
    __syncthreads();

    float ao0 = 0.f, ao1 = 0.f, ao2 = 0.f, ao3 = 0.f;
    for (int k = 0; k < 512; ++k) {
        float w = w2[k * CDIM + c];
        ao0 += s_mid[0][k] * w;
        ao1 += s_mid[1][k] * w;
        ao2 += s_mid[2][k] * w;
        ao3 += s_mid[3][k] * w;
    }
    float bb = b2[c];
    h[(m * NORI + pg * 4 + 0) * CDIM + c] += ao0 + bb;
    h[(m * NORI + pg * 4 + 1) * CDIM + c] += ao1 + bb;
    h[(m * NORI + pg * 4 + 2) * CDIM + c] += ao2 + bb;
    h[(m * NORI + pg * 4 + 3) * CDIM + c] += ao3 + bb;
}

// ---------------------------------------------------------------------------
extern "C" void kernel_launch(void* const* d_in, const int* in_sizes, int n_in,
                              void* d_out, int out_size, void* d_ws, size_t ws_size,
                              hipStream_t stream)
{
    const float* x        = (const float*)d_in[0];
    const float* pos      = (const float*)d_in[1];
    const float* bw1      = (const float*)d_in[2];
    const float* bb1      = (const float*)d_in[3];
    const float* bw2      = (const float*)d_in[4];
    const float* bb2      = (const float*)d_in[5];
    const float* fw1      = (const float*)d_in[6];
    const float* fb1      = (const float*)d_in[7];
    const float* fw2      = (const float*)d_in[8];
    const float* fb2      = (const float*)d_in[9];
    const float* emb_w    = (const float*)d_in[10];
    const float* kernel_w = (const float*)d_in[11];
    const float* fiber_w  = (const float*)d_in[12];
    const float* conv_b   = (const float*)d_in[13];
    const float* ln_g     = (const float*)d_in[14];
    const float* ln_b     = (const float*)d_in[15];
    const float* mlp_w1   = (const float*)d_in[16];
    const float* mlp_b1   = (const float*)d_in[17];
    const float* mlp_w2   = (const float*)d_in[18];
    const float* mlp_b2   = (const float*)d_in[19];

    float* h  = (float*)d_out;                      // [160,20,128]
    float* ws = (float*)d_ws;
    float* fk = ws;                                 // [2,20,20,128]
    float* x1 = ws + 2 * NORI * NORI * CDIM;        // [160,20,128]

    fk_kernel<<<2 * NORI * NORI, 128, 0, stream>>>(fw1, fb1, fw2, fb2, fiber_w, fk);
    h0_kernel<<<NPTS * NORI, 128, 0, stream>>>(x, emb_w, h);

    for (int l = 0; l < 2; ++l) {
        x1_kernel<<<NPTS * NORI, 256, 0, stream>>>(
            pos, h, bw1, bb1, bw2, bb2, kernel_w + l * CDIM * CDIM, x1);
        mlp_kernel<<<NPTS * NORI / 4, 128, 0, stream>>>(
            x1, fk + l * NORI * NORI * CDIM,
            conv_b + l * CDIM, ln_g + l * CDIM, ln_b + l * CDIM,
            mlp_w1 + l * CDIM * 4 * CDIM, mlp_b1 + l * 4 * CDIM,
            mlp_w2 + l * 4 * CDIM * CDIM, mlp_b2 + l * CDIM, h);
    }
}

// Round 4
// 1406.921 us; speedup vs baseline: 5.3534x; 5.3534x over previous
//
#include <hip/hip_runtime.h>
#include <math.h>

#define NORI 20
#define NPTS 160
#define CDIM 128
#define TWO_PI_OVER_O (6.28318530717958647692f / 20.0f)
#define SA 132            // s_act row stride (floats)
#define SW 132            // s_w row stride (floats)

__device__ __forceinline__ float gelu_exact(float x) {
    return 0.5f * x * (1.0f + erff(x * 0.70710678118654752440f));
}
__device__ __forceinline__ float4 ld4(const float* p) { return *(const float4*)p; }

#define FMA4(d, s, v) { d.x += (s)*(v).x; d.y += (s)*(v).y; d.z += (s)*(v).z; d.w += (s)*(v).w; }
#define MUL4ACC(d, a, b) { d.x += (a).x*(b).x; d.y += (a).y*(b).y; d.z += (a).z*(b).z; d.w += (a).w*(b).w; }
#define GELU4B(d, bias) { d.x = gelu_exact(d.x + (bias).x); d.y = gelu_exact(d.y + (bias).y); \
                          d.z = gelu_exact(d.z + (bias).z); d.w = gelu_exact(d.w + (bias).w); }

// ---------------------------------------------------------------------------
// fk[l,p,o,c]
// ---------------------------------------------------------------------------
__global__ __launch_bounds__(128) void fk_kernel(
    const float* __restrict__ fw1, const float* __restrict__ fb1,
    const float* __restrict__ fw2, const float* __restrict__ fb2,
    const float* __restrict__ fiber_w, float* __restrict__ fk)
{
    __shared__ float s_u[CDIM];
    __shared__ float s_z[CDIM];
    int bid = blockIdx.x;
    int l = bid / 400;
    int rem = bid % 400;
    int p = rem / 20, o = rem % 20;
    int j = threadIdx.x;

    float t = cosf(TWO_PI_OVER_O * (float)(p - o));
    float f1 = t * t, f2 = f1 * t;

    float u = gelu_exact(t * fw1[j] + f1 * fw1[CDIM + j] + f2 * fw1[2 * CDIM + j] + fb1[j]);
    s_u[j] = u;
    __syncthreads();

    float z0 = 0.f, z1 = 0.f, z2 = 0.f, z3 = 0.f;
    for (int i = 0; i < CDIM; i += 4) {
        z0 += s_u[i    ] * fw2[(i    ) * CDIM + j];
        z1 += s_u[i + 1] * fw2[(i + 1) * CDIM + j];
        z2 += s_u[i + 2] * fw2[(i + 2) * CDIM + j];
        z3 += s_u[i + 3] * fw2[(i + 3) * CDIM + j];
    }
    float z = gelu_exact(((z0 + z1) + (z2 + z3)) + fb2[j]);
    s_z[j] = z;
    __syncthreads();

    const float* fw = fiber_w + l * CDIM * CDIM;
    float a0 = 0.f, a1 = 0.f, a2 = 0.f, a3 = 0.f;
    for (int i = 0; i < CDIM; i += 4) {
        a0 += s_z[i    ] * fw[(i    ) * CDIM + j];
        a1 += s_z[i + 1] * fw[(i + 1) * CDIM + j];
        a2 += s_z[i + 2] * fw[(i + 2) * CDIM + j];
        a3 += s_z[i + 3] * fw[(i + 3) * CDIM + j];
    }
    fk[bid * CDIM + j] = (a0 + a1) + (a2 + a3);
}

// ---------------------------------------------------------------------------
// h0
// ---------------------------------------------------------------------------
__global__ __launch_bounds__(128) void h0_kernel(
    const float* __restrict__ x, const float* __restrict__ emb_w,
    float* __restrict__ h)
{
    int row = blockIdx.x;
    int j = threadIdx.x;
    const float* xr = x + row * 16;
    float acc = 0.f;
#pragma unroll
    for (int i = 0; i < 16; ++i) acc += xr[i] * emb_w[i * CDIM + j];
    h[row * CDIM + j] = acc;
}

// ---------------------------------------------------------------------------
// x1 kernel macros — everything expands in kernel scope; accumulator arrays
// are locals with only compile-time indices (never address-taken; the round-3
// version passed acc[][] into a function -> pointer decay -> scratch -> 16 GB
// of HBM spill traffic per dispatch).
// ---------------------------------------------------------------------------
#define GQUAD(ACC, Q, COMP, NR) { \
    float4 wa = ld4(wr + (Q) * SW); \
    float4 wv = ld4(wr + (Q) * SW + 4); \
    FMA4(ACC[0][0], a0.COMP, wa); FMA4(ACC[0][1], a0.COMP, wv); \
    if ((NR) > 1) { FMA4(ACC[1][0], a1.COMP, wa); FMA4(ACC[1][1], a1.COMP, wv); } \
    if ((NR) > 2) { FMA4(ACC[2][0], a2.COMP, wa); FMA4(ACC[2][1], a2.COMP, wv); } \
    if ((NR) > 3) { FMA4(ACC[3][0], a3.COMP, wa); FMA4(ACC[3][1], a3.COMP, wv); } }

// 128x128 weight GEMM over a tile of NR*16 activation rows.
// Single-buffered 32-row weight panels in s_w.
#define GEMM_PANELS(ACC, WPTR, NR) \
    _Pragma("unroll 1") \
    for (int pnl = 0; pnl < 4; ++pnl) { \
        const float* Wp = (WPTR) + pnl * 4096; \
        float4 w0_ = ld4(Wp + f0), w1_ = ld4(Wp + f1); \
        float4 w2_ = ld4(Wp + f2), w3_ = ld4(Wp + f3); \
        __syncthreads();                 /* prior s_w reads / s_act writes done */ \
        *(float4*)&s_w[swo0] = w0_; *(float4*)&s_w[swo1] = w1_; \
        *(float4*)&s_w[swo2] = w2_; *(float4*)&s_w[swo3] = w3_; \
        __syncthreads(); \
        const float* abase = s_act + pnl * 32; \
        _Pragma("unroll") \
        for (int i4 = 0; i4 < 8; ++i4) { \
            float4 a0, a1, a2, a3; \
            a0 = ld4(abase + rg * SA + i4 * 4); \
            if ((NR) > 1) a1 = ld4(abase + (rg + 16) * SA + i4 * 4); \
            if ((NR) > 2) a2 = ld4(abase + (rg + 32) * SA + i4 * 4); \
            if ((NR) > 3) a3 = ld4(abase + (rg + 48) * SA + i4 * 4); \
            const float* wr = s_w + (i4 * 4) * SW + c0; \
            GQUAD(ACC, 0, x, NR) GQUAD(ACC, 1, y, NR) \
            GQUAD(ACC, 2, z, NR) GQUAD(ACC, 3, w, NR) \
        } \
    }

#define TILE(NR, N0) { \
    __syncthreads();                     /* prior s_act readers done */ \
    _Pragma("unroll") \
    for (int r = 0; r < (NR); ++r) { \
        int n = (N0) + rg + 16 * r; \
        float rx = pos[2 * n] - pmx, ry = pos[2 * n + 1] - pmy; \
        float a = rx * ox + ry * oy; \
        float b = sqrtf(rx * rx + ry * ry) * fabsf(1.0f - a); \
        float a2 = a * a, ab = a * b, b2 = b * b; \
        float a3 = a2 * a, a2b = a2 * b, ab2 = ab * b, b3 = b2 * b; \
        float pv[14] = {a, b, a2, ab, ab, b2, a3, a2b, a2b, ab2, a2b, ab2, ab2, b3}; \
        float4 ua = {0.f,0.f,0.f,0.f}, ub = {0.f,0.f,0.f,0.f}; \
        _Pragma("unroll") \
        for (int i = 0; i < 14; ++i) { \
            float4 wa = ld4(&s_bw1[i * SW + c0]); \
            float4 wv = ld4(&s_bw1[i * SW + c0 + 4]); \
            FMA4(ua, pv[i], wa); \
            FMA4(ub, pv[i], wv); \
        } \
        float4 ba = ld4(&s_bb1[c0]), bbv = ld4(&s_bb1[c0 + 4]); \
        GELU4B(ua, ba); GELU4B(ub, bbv); \
        *(float4*)&s_act[(rg + 16 * r) * SA + c0] = ua; \
        *(float4*)&s_act[(rg + 16 * r) * SA + c0 + 4] = ub; \
    } \
    float4 acc[4][2]; \
    _Pragma("unroll") \
    for (int r = 0; r < 4; ++r) { acc[r][0] = {0.f,0.f,0.f,0.f}; acc[r][1] = {0.f,0.f,0.f,0.f}; } \
    GEMM_PANELS(acc, bw2, NR)            /* first panel barrier makes u visible */ \
    __syncthreads();                     /* all u-reads done before overwrite */ \
    { \
        float4 zba = ld4(&s_bb2[c0]), zbb = ld4(&s_bb2[c0 + 4]); \
        _Pragma("unroll") \
        for (int r = 0; r < (NR); ++r) { \
            float4 za = acc[r][0], zb = acc[r][1]; \
            GELU4B(za, zba); GELU4B(zb, zbb); \
            *(float4*)&s_act[(rg + 16 * r) * SA + c0] = za; \
            *(float4*)&s_act[(rg + 16 * r) * SA + c0 + 4] = zb; \
        } \
    } \
    float4 kacc[4][2]; \
    _Pragma("unroll") \
    for (int r = 0; r < 4; ++r) { kacc[r][0] = {0.f,0.f,0.f,0.f}; kacc[r][1] = {0.f,0.f,0.f,0.f}; } \
    GEMM_PANELS(kacc, kw, NR)            /* first panel barrier makes z visible */ \
    _Pragma("unroll") \
    for (int r = 0; r < (NR); ++r) { \
        int n = (N0) + rg + 16 * r; \
        const float* hp = h + (n * NORI + o) * CDIM + c0; \
        float4 ha = ld4(hp), hbv = ld4(hp + 4); \
        MUL4ACC(xa, kacc[r][0], ha); \
        MUL4ACC(xb, kacc[r][1], hbv); \
    } }

// ---------------------------------------------------------------------------
// x1[m,o,c] = sum_n (gelu(gelu(poly@bw1+bb1)@bw2+bb2) @ kw)[n,c] * h[n,o,c]
// one block per (m,o), 256 threads; tiles of 64,64,32 rows; 4x8 micro-tiles.
// rg = tid&15, cg = tid>>4: weight reads 4-unique + 16-broadcast (conflict-
// free, measured 0 in r3); activation reads 16-unique + 4-broadcast.
// ---------------------------------------------------------------------------
__global__ __launch_bounds__(256, 2) void x1_kernel(
    const float* __restrict__ pos, const float* __restrict__ h,
    const float* __restrict__ bw1, const float* __restrict__ bb1,
    const float* __restrict__ bw2, const float* __restrict__ bb2,
    const float* __restrict__ kw, float* __restrict__ x1)
{
    __shared__ float s_act[64 * SA];        // 33792 B
    __shared__ float s_w[32 * SW];          // 16896 B
    __shared__ float s_bw1[14 * SW];        // 7392 B
    __shared__ float s_bb1[CDIM];
    __shared__ float s_bb2[CDIM];

    const int tid = threadIdx.x;
    const int rg = tid & 15;        // row group
    const int cg = tid >> 4;        // col group (8 cols)
    const int c0 = cg << 3;

    // weight-panel staging offsets: thread stages 4 float4s = rows {w, w+8, w+16, w+24}
    const int f0 = tid * 4, f1 = f0 + 1024, f2 = f0 + 2048, f3 = f0 + 3072;
    const int wrow = tid >> 5, wcol = (tid & 31) * 4;
    const int swo0 = wrow * SW + wcol;
    const int swo1 = swo0 + 8 * SW;
    const int swo2 = swo0 + 16 * SW;
    const int swo3 = swo0 + 24 * SW;

    for (int e = tid; e < 14 * 128; e += 256) {
        int row = e >> 7, col = e & 127;
        s_bw1[row * SW + col] = bw1[e];
    }
    if (tid < 128) {
        s_bb1[tid] = bb1[tid];
        s_bb2[tid] = bb2[tid];
    }

    const int m = blockIdx.x / NORI;
    const int o = blockIdx.x % NORI;
    const float th = TWO_PI_OVER_O * (float)o;
    const float ox = cosf(th), oy = sinf(th);
    const float pmx = pos[2 * m], pmy = pos[2 * m + 1];

    float4 xa = {0.f, 0.f, 0.f, 0.f}, xb = {0.f, 0.f, 0.f, 0.f};

    TILE(4, 0)
    TILE(4, 64)
    TILE(2, 128)

    // ---- reduce the 16 row-group partials per column
    __syncthreads();
    *(float4*)&s_act[rg * SA + c0] = xa;
    *(float4*)&s_act[rg * SA + c0 + 4] = xb;
    __syncthreads();
    if (tid < 128) {
        float s = 0.f;
#pragma unroll
        for (int g = 0; g < 16; ++g) s += s_act[g * SA + tid];
        x1[(m * NORI + o) * CDIM + tid] = s;
    }
}

// ---------------------------------------------------------------------------
// fiber conv + LN + MLP + residual: 4 p-rows per block, grid = 160*5
// ---------------------------------------------------------------------------
__global__ __launch_bounds__(128) void mlp_kernel(
    const float* __restrict__ x1, const float* __restrict__ fk_l,
    const float* __restrict__ conv_b, const float* __restrict__ ln_g,
    const float* __restrict__ ln_b,
    const float* __restrict__ w1, const float* __restrict__ b1,
    const float* __restrict__ w2, const float* __restrict__ b2,
    float* __restrict__ h)
{
    __shared__ float s_xn[4][132];
    __shared__ float s_mid[4][520];
    __shared__ float s_s1[4][2], s_sq[4][2];

    const int c = threadIdx.x;
    const int m = blockIdx.x / 5, pg = blockIdx.x % 5;
    const int lane = c & 63, wid = c >> 6;

    float x1v[NORI];
#pragma unroll
    for (int o = 0; o < NORI; ++o) x1v[o] = x1[(m * NORI + o) * CDIM + c];

    float x2v[4];
#pragma unroll
    for (int rr = 0; rr < 4; ++rr) {
        int p = pg * 4 + rr;
        float x2 = 0.f;
#pragma unroll
        for (int o = 0; o < NORI; ++o) x2 += x1v[o] * fk_l[(p * NORI + o) * CDIM + c];
        x2 = x2 * (1.0f / 128.0f) + conv_b[c];
        x2v[rr] = x2;
        float s1 = x2, sq = x2 * x2;
        for (int off = 32; off; off >>= 1) {
            s1 += __shfl_down(s1, off, 64);
            sq += __shfl_down(sq, off, 64);
        }
        if (lane == 0) { s_s1[rr][wid] = s1; s_sq[rr][wid] = sq; }
    }
    __syncthreads();
#pragma unroll
    for (int rr = 0; rr < 4; ++rr) {
        float mu  = (s_s1[rr][0] + s_s1[rr][1]) * (1.0f / 128.0f);
        float var = (s_sq[rr][0] + s_sq[rr][1]) * (1.0f / 128.0f) - mu * mu;
        float xn = (x2v[rr] - mu) * rsqrtf(var + 1e-5f) * ln_g[c] + ln_b[c];
        s_xn[rr][c] = xn;
    }
    __syncthreads();

#pragma unroll
    for (int kq = 0; kq < 4; ++kq) {
        int k = kq * CDIM + c;
        float b = b1[k];
        float ac0 = b, ac1 = b, ac2 = b, ac3 = b;
        for (int i = 0; i < CDIM; ++i) {
            float w = w1[i * 512 + k];
            ac0 += s_xn[0][i] * w;
            ac1 += s_xn[1][i] * w;
            ac2 += s_xn[2][i] * w;
            ac3 += s_xn[3][i] * w;
        }
        s_mid[0][k] = gelu_exact(ac0);
        s_mid[1][k] = gelu_exact(ac1);
        s_mid[2][k] = gelu_exact(ac2);
        s_mid[3][k] = gelu_exact(ac3);
    }
    __syncthreads();

    float ao0 = 0.f, ao1 = 0.f, ao2 = 0.f, ao3 = 0.f;
    for (int k = 0; k < 512; ++k) {
        float w = w2[k * CDIM + c];
        ao0 += s_mid[0][k] * w;
        ao1 += s_mid[1][k] * w;
        ao2 += s_mid[2][k] * w;
        ao3 += s_mid[3][k] * w;
    }
    float bb = b2[c];
    h[(m * NORI + pg * 4 + 0) * CDIM + c] += ao0 + bb;
    h[(m * NORI + pg * 4 + 1) * CDIM + c] += ao1 + bb;
    h[(m * NORI + pg * 4 + 2) * CDIM + c] += ao2 + bb;
    h[(m * NORI + pg * 4 + 3) * CDIM + c] += ao3 + bb;
}

// ---------------------------------------------------------------------------
extern "C" void kernel_launch(void* const* d_in, const int* in_sizes, int n_in,
                              void* d_out, int out_size, void* d_ws, size_t ws_size,
                              hipStream_t stream)
{
    const float* x        = (const float*)d_in[0];
    const float* pos      = (const float*)d_in[1];
    const float* bw1      = (const float*)d_in[2];
    const float* bb1      = (const float*)d_in[3];
    const float* bw2      = (const float*)d_in[4];
    const float* bb2      = (const float*)d_in[5];
    const float* fw1      = (const float*)d_in[6];
    const float* fb1      = (const float*)d_in[7];
    const float* fw2      = (const float*)d_in[8];
    const float* fb2      = (const float*)d_in[9];
    const float* emb_w    = (const float*)d_in[10];
    const float* kernel_w = (const float*)d_in[11];
    const float* fiber_w  = (const float*)d_in[12];
    const float* conv_b   = (const float*)d_in[13];
    const float* ln_g     = (const float*)d_in[14];
    const float* ln_b     = (const float*)d_in[15];
    const float* mlp_w1   = (const float*)d_in[16];
    const float* mlp_b1   = (const float*)d_in[17];
    const float* mlp_w2   = (const float*)d_in[18];
    const float* mlp_b2   = (const float*)d_in[19];

    float* h  = (float*)d_out;                      // [160,20,128]
    float* ws = (float*)d_ws;
    float* fk = ws;                                 // [2,20,20,128]
    float* x1 = ws + 2 * NORI * NORI * CDIM;        // [160,20,128]

    fk_kernel<<<2 * NORI * NORI, 128, 0, stream>>>(fw1, fb1, fw2, fb2, fiber_w, fk);
    h0_kernel<<<NPTS * NORI, 128, 0, stream>>>(x, emb_w, h);

    for (int l = 0; l < 2; ++l) {
        x1_kernel<<<NPTS * NORI, 256, 0, stream>>>(
            pos, h, bw1, bb1, bw2, bb2, kernel_w + l * CDIM * CDIM, x1);
        mlp_kernel<<<NPTS * NORI / 4, 128, 0, stream>>>(
            x1, fk + l * NORI * NORI * CDIM,
            conv_b + l * CDIM, ln_g + l * CDIM, ln_b + l * CDIM,
            mlp_w1 + l * CDIM * 4 * CDIM, mlp_b1 + l * 4 * CDIM,
            mlp_w2 + l * 4 * CDIM * CDIM, mlp_b2 + l * CDIM, h);
    }
}

// Round 5
// 1343.970 us; speedup vs baseline: 5.6041x; 1.0468x over previous
//
#include <hip/hip_runtime.h>
#include <math.h>

#define NORI 20
#define NPTS 160
#define CDIM 128
#define TWO_PI_OVER_O (6.28318530717958647692f / 20.0f)
#define SA 132            // s_act row stride (floats)
#define SW 132            // s_bw1 row stride (floats)

__device__ __forceinline__ float gelu_exact(float x) {
    return 0.5f * x * (1.0f + erff(x * 0.70710678118654752440f));
}
__device__ __forceinline__ float4 ld4(const float* p) { return *(const float4*)p; }

#define FMA4(d, s, v) { d.x += (s)*(v).x; d.y += (s)*(v).y; d.z += (s)*(v).z; d.w += (s)*(v).w; }
#define MUL4ACC(d, a, b) { d.x += (a).x*(b).x; d.y += (a).y*(b).y; d.z += (a).z*(b).z; d.w += (a).w*(b).w; }
#define GELU4(d) { d.x = gelu_exact(d.x); d.y = gelu_exact(d.y); \
                   d.z = gelu_exact(d.z); d.w = gelu_exact(d.w); }
#define GELU4B(d, bias) { d.x = gelu_exact(d.x + (bias).x); d.y = gelu_exact(d.y + (bias).y); \
                          d.z = gelu_exact(d.z + (bias).z); d.w = gelu_exact(d.w + (bias).w); }

// ---------------------------------------------------------------------------
// fk[l,p,o,c]
// ---------------------------------------------------------------------------
__global__ __launch_bounds__(128) void fk_kernel(
    const float* __restrict__ fw1, const float* __restrict__ fb1,
    const float* __restrict__ fw2, const float* __restrict__ fb2,
    const float* __restrict__ fiber_w, float* __restrict__ fk)
{
    __shared__ float s_u[CDIM];
    __shared__ float s_z[CDIM];
    int bid = blockIdx.x;
    int l = bid / 400;
    int rem = bid % 400;
    int p = rem / 20, o = rem % 20;
    int j = threadIdx.x;

    float t = cosf(TWO_PI_OVER_O * (float)(p - o));
    float f1 = t * t, f2 = f1 * t;

    float u = gelu_exact(t * fw1[j] + f1 * fw1[CDIM + j] + f2 * fw1[2 * CDIM + j] + fb1[j]);
    s_u[j] = u;
    __syncthreads();

    float z0 = 0.f, z1 = 0.f, z2 = 0.f, z3 = 0.f;
    for (int i = 0; i < CDIM; i += 4) {
        z0 += s_u[i    ] * fw2[(i    ) * CDIM + j];
        z1 += s_u[i + 1] * fw2[(i + 1) * CDIM + j];
        z2 += s_u[i + 2] * fw2[(i + 2) * CDIM + j];
        z3 += s_u[i + 3] * fw2[(i + 3) * CDIM + j];
    }
    float z = gelu_exact(((z0 + z1) + (z2 + z3)) + fb2[j]);
    s_z[j] = z;
    __syncthreads();

    const float* fw = fiber_w + l * CDIM * CDIM;
    float a0 = 0.f, a1 = 0.f, a2 = 0.f, a3 = 0.f;
    for (int i = 0; i < CDIM; i += 4) {
        a0 += s_z[i    ] * fw[(i    ) * CDIM + j];
        a1 += s_z[i + 1] * fw[(i + 1) * CDIM + j];
        a2 += s_z[i + 2] * fw[(i + 2) * CDIM + j];
        a3 += s_z[i + 3] * fw[(i + 3) * CDIM + j];
    }
    fk[bid * CDIM + j] = (a0 + a1) + (a2 + a3);
}

// ---------------------------------------------------------------------------
// h0
// ---------------------------------------------------------------------------
__global__ __launch_bounds__(128) void h0_kernel(
    const float* __restrict__ x, const float* __restrict__ emb_w,
    float* __restrict__ h)
{
    int row = blockIdx.x;
    int j = threadIdx.x;
    const float* xr = x + row * 16;
    float acc = 0.f;
#pragma unroll
    for (int i = 0; i < 16; ++i) acc += xr[i] * emb_w[i * CDIM + j];
    h[row * CDIM + j] = acc;
}

// ---------------------------------------------------------------------------
// x1 kernel — 8x8 micro-tile, weights streamed from global (L2-resident),
// activations in LDS, NO register arrays anywhere (r3: array->function =
// scratch; r4: pv[14] array = 293 MB scratch writes).
// ---------------------------------------------------------------------------

// u = gelu(monomials @ folded_bw1 + bb1), one row
#define UF(I, S) { \
    float4 uwa = ld4(&s_bw1[(I) * SW + c0]); \
    float4 uwb = ld4(&s_bw1[(I) * SW + c0 + 4]); \
    FMA4(ua, S, uwa); FMA4(ub, S, uwb); }

#define UROW(R, N0) { \
    const int n_ = (N0) + rg + 16 * (R); \
    float rx_ = pos[2 * n_] - pmx, ry_ = pos[2 * n_ + 1] - pmy; \
    float ia_ = rx_ * ox + ry_ * oy; \
    float ib_ = sqrtf(rx_ * rx_ + ry_ * ry_) * fabsf(1.0f - ia_); \
    float q2a_ = ia_ * ia_, q2m_ = ia_ * ib_, q2b_ = ib_ * ib_; \
    float q3a_ = q2a_ * ia_, q3m_ = q2a_ * ib_, q3n_ = q2m_ * ib_, q3b_ = q2b_ * ib_; \
    float4 ua = ld4(&s_bb1[c0]); \
    float4 ub = ld4(&s_bb1[c0 + 4]); \
    UF(0, ia_) UF(1, ib_) UF(2, q2a_) UF(3, q2m_) UF(4, q2b_) \
    UF(5, q3a_) UF(6, q3m_) UF(7, q3n_) UF(8, q3b_) \
    GELU4(ua) GELU4(ub) \
    *(float4*)&s_act[(rg + 16 * (R)) * SA + c0] = ua; \
    *(float4*)&s_act[(rg + 16 * (R)) * SA + c0 + 4] = ub; }

// one activation row x 4 k-values x 8 cols of FMAs
#define GROW(R) { \
    float4 a_ = ld4(ab_ + (R) * 16 * SA); \
    FMA4(acc##R##a, a_.x, w0a); FMA4(acc##R##b, a_.x, w0b); \
    FMA4(acc##R##a, a_.y, w1a); FMA4(acc##R##b, a_.y, w1b); \
    FMA4(acc##R##a, a_.z, w2a); FMA4(acc##R##b, a_.z, w2b); \
    FMA4(acc##R##a, a_.w, w3a); FMA4(acc##R##b, a_.w, w3b); }

// full k=128 GEMM, weights direct from global (L2 broadcast)
#define GEMM_G(WPTR, NR) \
    _Pragma("unroll 4") \
    for (int kq = 0; kq < 32; ++kq) { \
        const float* wp = (WPTR) + kq * 4 * CDIM + c0; \
        const float4 w0a = ld4(wp),              w0b = ld4(wp + 4); \
        const float4 w1a = ld4(wp + CDIM),       w1b = ld4(wp + CDIM + 4); \
        const float4 w2a = ld4(wp + 2 * CDIM),   w2b = ld4(wp + 2 * CDIM + 4); \
        const float4 w3a = ld4(wp + 3 * CDIM),   w3b = ld4(wp + 3 * CDIM + 4); \
        const float* ab_ = &s_act[rg * SA + kq * 4]; \
        GROW(0) \
        if ((NR) > 1) GROW(1) \
        if ((NR) > 2) GROW(2) \
        if ((NR) > 3) GROW(3) \
        if ((NR) > 4) GROW(4) \
        if ((NR) > 5) GROW(5) \
        if ((NR) > 6) GROW(6) \
        if ((NR) > 7) GROW(7) \
    }

// z = gelu(acc + bb2) -> s_act, then zero acc for the next GEMM
#define ZROW(R) { \
    float4 ta_ = acc##R##a, tb_ = acc##R##b; \
    GELU4B(ta_, zba) GELU4B(tb_, zbb) \
    *(float4*)&s_act[(rg + 16 * (R)) * SA + c0] = ta_; \
    *(float4*)&s_act[(rg + 16 * (R)) * SA + c0 + 4] = tb_; \
    acc##R##a = zf4_; acc##R##b = zf4_; }

// xacc += kern * h
#define HROW(R, N0) { \
    const float* hp_ = h + (((N0) + rg + 16 * (R)) * NORI + o) * CDIM + c0; \
    float4 ha_ = ld4(hp_), hb_ = ld4(hp_ + 4); \
    MUL4ACC(xacc_a, acc##R##a, ha_); \
    MUL4ACC(xacc_b, acc##R##b, hb_); }

#define X1_TILE(NR, N0) { \
    __syncthreads();                      /* prior s_act readers done */ \
    UROW(0, N0) \
    if ((NR) > 1) UROW(1, N0) \
    if ((NR) > 2) UROW(2, N0) \
    if ((NR) > 3) UROW(3, N0) \
    if ((NR) > 4) UROW(4, N0) \
    if ((NR) > 5) UROW(5, N0) \
    if ((NR) > 6) UROW(6, N0) \
    if ((NR) > 7) UROW(7, N0) \
    __syncthreads();                      /* u visible */ \
    const float4 zf4_ = {0.f, 0.f, 0.f, 0.f}; \
    float4 acc0a = zf4_, acc0b = zf4_, acc1a = zf4_, acc1b = zf4_; \
    float4 acc2a = zf4_, acc2b = zf4_, acc3a = zf4_, acc3b = zf4_; \
    float4 acc4a = zf4_, acc4b = zf4_, acc5a = zf4_, acc5b = zf4_; \
    float4 acc6a = zf4_, acc6b = zf4_, acc7a = zf4_, acc7b = zf4_; \
    GEMM_G(bw2, NR) \
    __syncthreads();                      /* u reads done before overwrite */ \
    { \
        float4 zba = ld4(&s_bb2[c0]), zbb = ld4(&s_bb2[c0 + 4]); \
        ZROW(0) \
        if ((NR) > 1) ZROW(1) \
        if ((NR) > 2) ZROW(2) \
        if ((NR) > 3) ZROW(3) \
        if ((NR) > 4) ZROW(4) \
        if ((NR) > 5) ZROW(5) \
        if ((NR) > 6) ZROW(6) \
        if ((NR) > 7) ZROW(7) \
    } \
    __syncthreads();                      /* z visible */ \
    GEMM_G(kw, NR) \
    HROW(0, N0) \
    if ((NR) > 1) HROW(1, N0) \
    if ((NR) > 2) HROW(2, N0) \
    if ((NR) > 3) HROW(3, N0) \
    if ((NR) > 4) HROW(4, N0) \
    if ((NR) > 5) HROW(5, N0) \
    if ((NR) > 6) HROW(6, N0) \
    if ((NR) > 7) HROW(7, N0) \
}

// ---------------------------------------------------------------------------
// x1[m,o,c] = sum_n (gelu(gelu(poly@bw1+bb1)@bw2+bb2) @ kw)[n,c] * h[n,o,c]
// one block per (m,o), 256 threads; tiles of 128 + 32 rows; 8x8 micro-tiles.
// rg = tid&15, cg = tid>>4. act LDS reads: 16 unique rows stride 132B -> 2-way
// bank aliasing (free, measured 0 conflicts in r3/r4 with same pattern).
// ---------------------------------------------------------------------------
__global__ __launch_bounds__(256, 2) void x1_kernel(
    const float* __restrict__ pos, const float* __restrict__ h,
    const float* __restrict__ bw1, const float* __restrict__ bb1,
    const float* __restrict__ bw2, const float* __restrict__ bb2,
    const float* __restrict__ kw, float* __restrict__ x1)
{
    __shared__ float s_act[128 * SA];       // 67584 B
    __shared__ float s_bw1[9 * SW];         // 4752 B  (folded monomial weights)
    __shared__ float s_bb1[CDIM];
    __shared__ float s_bb2[CDIM];

    const int tid = threadIdx.x;
    const int rg = tid & 15;        // row group
    const int cg = tid >> 4;        // col group (8 cols)
    const int c0 = cg << 3;

    // fold the 14 PolynomialFeatures rows into 9 distinct monomials:
    // rows {3,4}->ab, {7,8,10}->a2b, {9,11,12}->ab2
    if (tid < CDIM) {
        const int c = tid;
        s_bw1[0 * SW + c] = bw1[0 * CDIM + c];
        s_bw1[1 * SW + c] = bw1[1 * CDIM + c];
        s_bw1[2 * SW + c] = bw1[2 * CDIM + c];
        s_bw1[3 * SW + c] = bw1[3 * CDIM + c] + bw1[4 * CDIM + c];
        s_bw1[4 * SW + c] = bw1[5 * CDIM + c];
        s_bw1[5 * SW + c] = bw1[6 * CDIM + c];
        s_bw1[6 * SW + c] = bw1[7 * CDIM + c] + bw1[8 * CDIM + c] + bw1[10 * CDIM + c];
        s_bw1[7 * SW + c] = bw1[9 * CDIM + c] + bw1[11 * CDIM + c] + bw1[12 * CDIM + c];
        s_bw1[8 * SW + c] = bw1[13 * CDIM + c];
        s_bb1[c] = bb1[c];
        s_bb2[c] = bb2[c];
    }

    const int m = blockIdx.x / NORI;
    const int o = blockIdx.x % NORI;
    const float th = TWO_PI_OVER_O * (float)o;
    const float ox = cosf(th), oy = sinf(th);
    const float pmx = pos[2 * m], pmy = pos[2 * m + 1];

    float4 xacc_a = {0.f, 0.f, 0.f, 0.f}, xacc_b = {0.f, 0.f, 0.f, 0.f};

    X1_TILE(8, 0)           // rows 0..127  (first barrier covers staging too)
    X1_TILE(2, 128)         // rows 128..159

    // ---- reduce the 16 row-group partials per column
    __syncthreads();
    *(float4*)&s_act[rg * SA + c0] = xacc_a;
    *(float4*)&s_act[rg * SA + c0 + 4] = xacc_b;
    __syncthreads();
    if (tid < CDIM) {
        float s = 0.f;
#pragma unroll
        for (int g = 0; g < 16; ++g) s += s_act[g * SA + tid];
        x1[(m * NORI + o) * CDIM + tid] = s;
    }
}

// ---------------------------------------------------------------------------
// fiber conv + LN + MLP + residual: 4 p-rows per block, grid = 160*5
// ---------------------------------------------------------------------------
__global__ __launch_bounds__(128) void mlp_kernel(
    const float* __restrict__ x1, const float* __restrict__ fk_l,
    const float* __restrict__ conv_b, const float* __restrict__ ln_g,
    const float* __restrict__ ln_b,
    const float* __restrict__ w1, const float* __restrict__ b1,
    const float* __restrict__ w2, const float* __restrict__ b2,
    float* __restrict__ h)
{
    __shared__ float s_xn[4][132];
    __shared__ float s_mid[4][520];
    __shared__ float s_s1[4][2], s_sq[4][2];

    const int c = threadIdx.x;
    const int m = blockIdx.x / 5, pg = blockIdx.x % 5;
    const int lane = c & 63, wid = c >> 6;

    float x1v[NORI];
#pragma unroll
    for (int o = 0; o < NORI; ++o) x1v[o] = x1[(m * NORI + o) * CDIM + c];

    float x2v[4];
#pragma unroll
    for (int rr = 0; rr < 4; ++rr) {
        int p = pg * 4 + rr;
        float x2 = 0.f;
#pragma unroll
        for (int o = 0; o < NORI; ++o) x2 += x1v[o] * fk_l[(p * NORI + o) * CDIM + c];
        x2 = x2 * (1.0f / 128.0f) + conv_b[c];
        x2v[rr] = x2;
        float s1 = x2, sq = x2 * x2;
        for (int off = 32; off; off >>= 1) {
            s1 += __shfl_down(s1, off, 64);
            sq += __shfl_down(sq, off, 64);
        }
        if (lane == 0) { s_s1[rr][wid] = s1; s_sq[rr][wid] = sq; }
    }
    __syncthreads();
#pragma unroll
    for (int rr = 0; rr < 4; ++rr) {
        float mu  = (s_s1[rr][0] + s_s1[rr][1]) * (1.0f / 128.0f);
        float var = (s_sq[rr][0] + s_sq[rr][1]) * (1.0f / 128.0f) - mu * mu;
        float xn = (x2v[rr] - mu) * rsqrtf(var + 1e-5f) * ln_g[c] + ln_b[c];
        s_xn[rr][c] = xn;
    }
    __syncthreads();

#pragma unroll
    for (int kq = 0; kq < 4; ++kq) {
        int k = kq * CDIM + c;
        float b = b1[k];
        float ac0 = b, ac1 = b, ac2 = b, ac3 = b;
        for (int i = 0; i < CDIM; ++i) {
            float w = w1[i * 512 + k];
            ac0 += s_xn[0][i] * w;
            ac1 += s_xn[1][i] * w;
            ac2 += s_xn[2][i] * w;
            ac3 += s_xn[3][i] * w;
        }
        s_mid[0][k] = gelu_exact(ac0);
        s_mid[1][k] = gelu_exact(ac1);
        s_mid[2][k] = gelu_exact(ac2);
        s_mid[3][k] = gelu_exact(ac3);
    }
    __syncthreads();

    float ao0 = 0.f, ao1 = 0.f, ao2 = 0.f, ao3 = 0.f;
    for (int k = 0; k < 512; ++k) {
        float w = w2[k * CDIM + c];
        ao0 += s_mid[0][k] * w;
        ao1 += s_mid[1][k] * w;
        ao2 += s_mid[2][k] * w;
        ao3 += s_mid[3][k] * w;
    }
    float bb = b2[c];
    h[(m * NORI + pg * 4 + 0) * CDIM + c] += ao0 + bb;
    h[(m * NORI + pg * 4 + 1) * CDIM + c] += ao1 + bb;
    h[(m * NORI + pg * 4 + 2) * CDIM + c] += ao2 + bb;
    h[(m * NORI + pg * 4 + 3) * CDIM + c] += ao3 + bb;
}

// ---------------------------------------------------------------------------
extern "C" void kernel_launch(void* const* d_in, const int* in_sizes, int n_in,
                              void* d_out, int out_size, void* d_ws, size_t ws_size,
                              hipStream_t stream)
{
    const float* x        = (const float*)d_in[0];
    const float* pos      = (const float*)d_in[1];
    const float* bw1      = (const float*)d_in[2];
    const float* bb1      = (const float*)d_in[3];
    const float* bw2      = (const float*)d_in[4];
    const float* bb2      = (const float*)d_in[5];
    const float* fw1      = (const float*)d_in[6];
    const float* fb1      = (const float*)d_in[7];
    const float* fw2      = (const float*)d_in[8];
    const float* fb2      = (const float*)d_in[9];
    const float* emb_w    = (const float*)d_in[10];
    const float* kernel_w = (const float*)d_in[11];
    const float* fiber_w  = (const float*)d_in[12];
    const float* conv_b   = (const float*)d_in[13];
    const float* ln_g     = (const float*)d_in[14];
    const float* ln_b     = (const float*)d_in[15];
    const float* mlp_w1   = (const float*)d_in[16];
    const float* mlp_b1   = (const float*)d_in[17];
    const float* mlp_w2   = (const float*)d_in[18];
    const float* mlp_b2   = (const float*)d_in[19];

    float* h  = (float*)d_out;                      // [160,20,128]
    float* ws = (float*)d_ws;
    float* fk = ws;                                 // [2,20,20,128]
    float* x1 = ws + 2 * NORI * NORI * CDIM;        // [160,20,128]

    fk_kernel<<<2 * NORI * NORI, 128, 0, stream>>>(fw1, fb1, fw2, fb2, fiber_w, fk);
    h0_kernel<<<NPTS * NORI, 128, 0, stream>>>(x, emb_w, h);

    for (int l = 0; l < 2; ++l) {
        x1_kernel<<<NPTS * NORI, 256, 0, stream>>>(
            pos, h, bw1, bb1, bw2, bb2, kernel_w + l * CDIM * CDIM, x1);
        mlp_kernel<<<NPTS * NORI / 4, 128, 0, stream>>>(
            x1, fk + l * NORI * NORI * CDIM,
            conv_b + l * CDIM, ln_g + l * CDIM, ln_b + l * CDIM,
            mlp_w1 + l * CDIM * 4 * CDIM, mlp_b1 + l * 4 * CDIM,
            mlp_w2 + l * 4 * CDIM * CDIM, mlp_b2 + l * CDIM, h);
    }
}

// Round 9
// 511.202 us; speedup vs baseline: 14.7335x; 2.6290x over previous
//
#include <hip/hip_runtime.h>
#include <math.h>

#define NORI 20
#define NPTS 160
#define CDIM 128
#define TWO_PI_OVER_O (6.28318530717958647692f / 20.0f)
#define SW 132           // fp32 LDS row stride (s_bw1)
#define SAS 136          // s_act row stride in ushorts (f16), 272 B
#define SCL 256.0f       // activation storage scale (exact pow2)
#define ISCL 0.00390625f // 1/256

typedef __attribute__((ext_vector_type(8))) _Float16 half8v;
typedef __attribute__((ext_vector_type(4))) float float4v;

__device__ __forceinline__ float gelu_exact(float x) {
    return 0.5f * x * (1.0f + erff(x * 0.70710678118654752440f));
}
__device__ __forceinline__ float4 ld4(const float* p) { return *(const float4*)p; }
__device__ __forceinline__ unsigned short f16b(float f) {
    _Float16 h = (_Float16)f;                 // RNE convert
    return __builtin_bit_cast(unsigned short, h);
}
__device__ __forceinline__ float f16tof(unsigned short u) {
    return (float)__builtin_bit_cast(_Float16, u);
}

#define FMA4(d, s, v) { d.x += (s)*(v).x; d.y += (s)*(v).y; d.z += (s)*(v).z; d.w += (s)*(v).w; }
#define GELU4(d) { d.x = gelu_exact(d.x); d.y = gelu_exact(d.y); \
                   d.z = gelu_exact(d.z); d.w = gelu_exact(d.w); }

// ---------------------------------------------------------------------------
// fk[l,p,o,c]  (stored f16; |fk| ~ O(10) well within f16 range)
// ---------------------------------------------------------------------------
__global__ __launch_bounds__(128) void fk_kernel(
    const float* __restrict__ fw1, const float* __restrict__ fb1,
    const float* __restrict__ fw2, const float* __restrict__ fb2,
    const float* __restrict__ fiber_w, unsigned short* __restrict__ fk)
{
    __shared__ float s_u[CDIM];
    __shared__ float s_z[CDIM];
    int bid = blockIdx.x;
    int l = bid / 400;
    int rem = bid % 400;
    int p = rem / 20, o = rem % 20;
    int j = threadIdx.x;

    float t = cosf(TWO_PI_OVER_O * (float)(p - o));
    float f1 = t * t, f2 = f1 * t;

    float u = gelu_exact(t * fw1[j] + f1 * fw1[CDIM + j] + f2 * fw1[2 * CDIM + j] + fb1[j]);
    s_u[j] = u;
    __syncthreads();

    float z0 = 0.f, z1 = 0.f, z2 = 0.f, z3 = 0.f;
    for (int i = 0; i < CDIM; i += 4) {
        z0 += s_u[i    ] * fw2[(i    ) * CDIM + j];
        z1 += s_u[i + 1] * fw2[(i + 1) * CDIM + j];
        z2 += s_u[i + 2] * fw2[(i + 2) * CDIM + j];
        z3 += s_u[i + 3] * fw2[(i + 3) * CDIM + j];
    }
    float z = gelu_exact(((z0 + z1) + (z2 + z3)) + fb2[j]);
    s_z[j] = z;
    __syncthreads();

    const float* fw = fiber_w + l * CDIM * CDIM;
    float a0 = 0.f, a1 = 0.f, a2 = 0.f, a3 = 0.f;
    for (int i = 0; i < CDIM; i += 4) {
        a0 += s_z[i    ] * fw[(i    ) * CDIM + j];
        a1 += s_z[i + 1] * fw[(i + 1) * CDIM + j];
        a2 += s_z[i + 2] * fw[(i + 2) * CDIM + j];
        a3 += s_z[i + 3] * fw[(i + 3) * CDIM + j];
    }
    fk[bid * CDIM + j] = f16b((a0 + a1) + (a2 + a3));
}

// ---------------------------------------------------------------------------
// h0
// ---------------------------------------------------------------------------
__global__ __launch_bounds__(128) void h0_kernel(
    const float* __restrict__ x, const float* __restrict__ emb_w,
    float* __restrict__ h)
{
    int row = blockIdx.x;
    int j = threadIdx.x;
    const float* xr = x + row * 16;
    float acc = 0.f;
#pragma unroll
    for (int i = 0; i < 16; ++i) acc += xr[i] * emb_w[i * CDIM + j];
    h[row * CDIM + j] = acc;
}

// ---------------------------------------------------------------------------
// wt: f16 transposed weights wt[mat][c][k] = f16(w[k][c]); |w| ≤ ~1 — safe
// ---------------------------------------------------------------------------
__global__ __launch_bounds__(128) void wt_kernel(
    const float* __restrict__ bw2, const float* __restrict__ kernel_w,
    unsigned short* __restrict__ wt)
{
    int b = blockIdx.x;            // mat*128 + c
    int mat = b >> 7, c = b & 127;
    const float* src = (mat == 0) ? bw2 : (kernel_w + (mat - 1) * CDIM * CDIM);
    int k = threadIdx.x;
    wt[(mat * CDIM + c) * CDIM + k] = f16b(src[k * CDIM + c]);
}

// ---------------------------------------------------------------------------
// x1 kernel — MFMA path (fp16 operands SCALED by 1/256, fp32 accum).
// r8 NaN root cause: u reaches ~1e6 > f16 max 65504. Storage scale u/256,
// z/256 keeps everything ≤ ~2e4; the 256 is unfolded in fp32 epilogues.
// mfma 16x16x32 layouts (shape-determined, dtype-independent):
// A: row=lane&15, k=(lane>>4)*8+e;  B: col=lane&15, k=(lane>>4)*8+e;
// C/D: col=lane&15, row=(lane>>4)*4+reg  [m89-verified].
// ---------------------------------------------------------------------------
#define FOR_BANDS(X) X(0) X(1) X(2) X(3) X(4) X(5) X(6) X(7) X(8) X(9)

#define DECL_ACC(B) float4v acc##B##_0 = {0.f,0.f,0.f,0.f}, acc##B##_1 = {0.f,0.f,0.f,0.f};

#define LDB(PTR, COL, KT) (*(const half8v*)((PTR) + (COL) * CDIM + (KT) * 32 + lh8))

#define LOADB(P, PTR) \
    half8v P##0_0 = LDB(PTR, col0, 0), P##0_1 = LDB(PTR, col1, 0); \
    half8v P##1_0 = LDB(PTR, col0, 1), P##1_1 = LDB(PTR, col1, 1); \
    half8v P##2_0 = LDB(PTR, col0, 2), P##2_1 = LDB(PTR, col1, 2); \
    half8v P##3_0 = LDB(PTR, col0, 3), P##3_1 = LDB(PTR, col1, 3);

#define G_BAND(B, P) { \
    const unsigned short* ar_ = s_act + (B) * 16 * SAS + abase; \
    half8v a0_ = *(const half8v*)(ar_); \
    half8v a1_ = *(const half8v*)(ar_ + 32); \
    half8v a2_ = *(const half8v*)(ar_ + 64); \
    half8v a3_ = *(const half8v*)(ar_ + 96); \
    acc##B##_0 = __builtin_amdgcn_mfma_f32_16x16x32_f16(a0_, P##0_0, acc##B##_0, 0, 0, 0); \
    acc##B##_1 = __builtin_amdgcn_mfma_f32_16x16x32_f16(a0_, P##0_1, acc##B##_1, 0, 0, 0); \
    acc##B##_0 = __builtin_amdgcn_mfma_f32_16x16x32_f16(a1_, P##1_0, acc##B##_0, 0, 0, 0); \
    acc##B##_1 = __builtin_amdgcn_mfma_f32_16x16x32_f16(a1_, P##1_1, acc##B##_1, 0, 0, 0); \
    acc##B##_0 = __builtin_amdgcn_mfma_f32_16x16x32_f16(a2_, P##2_0, acc##B##_0, 0, 0, 0); \
    acc##B##_1 = __builtin_amdgcn_mfma_f32_16x16x32_f16(a2_, P##2_1, acc##B##_1, 0, 0, 0); \
    acc##B##_0 = __builtin_amdgcn_mfma_f32_16x16x32_f16(a3_, P##3_0, acc##B##_0, 0, 0, 0); \
    acc##B##_1 = __builtin_amdgcn_mfma_f32_16x16x32_f16(a3_, P##3_1, acc##B##_1, 0, 0, 0); }

#define G1(B) G_BAND(B, bwf)
#define G2(B) G_BAND(B, kwf)

// z = gelu(256*acc + bb2), store z/256 as f16
#define ZW_BAND(B) { \
    int rb_ = (B) * 16 + lh4; \
    s_act[(rb_ + 0) * SAS + col0] = f16b(gelu_exact(SCL * acc##B##_0.x + zb0) * ISCL); \
    s_act[(rb_ + 1) * SAS + col0] = f16b(gelu_exact(SCL * acc##B##_0.y + zb0) * ISCL); \
    s_act[(rb_ + 2) * SAS + col0] = f16b(gelu_exact(SCL * acc##B##_0.z + zb0) * ISCL); \
    s_act[(rb_ + 3) * SAS + col0] = f16b(gelu_exact(SCL * acc##B##_0.w + zb0) * ISCL); \
    s_act[(rb_ + 0) * SAS + col1] = f16b(gelu_exact(SCL * acc##B##_1.x + zb1) * ISCL); \
    s_act[(rb_ + 1) * SAS + col1] = f16b(gelu_exact(SCL * acc##B##_1.y + zb1) * ISCL); \
    s_act[(rb_ + 2) * SAS + col1] = f16b(gelu_exact(SCL * acc##B##_1.z + zb1) * ISCL); \
    s_act[(rb_ + 3) * SAS + col1] = f16b(gelu_exact(SCL * acc##B##_1.w + zb1) * ISCL); \
    acc##B##_0 = vzero; acc##B##_1 = vzero; }

#define H_BAND(B) { \
    int nb_ = (B) * 16 + lh4; \
    xacc0 += acc##B##_0.x * hb0[(nb_ + 0) * 2560]; \
    xacc0 += acc##B##_0.y * hb0[(nb_ + 1) * 2560]; \
    xacc0 += acc##B##_0.z * hb0[(nb_ + 2) * 2560]; \
    xacc0 += acc##B##_0.w * hb0[(nb_ + 3) * 2560]; \
    xacc1 += acc##B##_1.x * hb1[(nb_ + 0) * 2560]; \
    xacc1 += acc##B##_1.y * hb1[(nb_ + 1) * 2560]; \
    xacc1 += acc##B##_1.z * hb1[(nb_ + 2) * 2560]; \
    xacc1 += acc##B##_1.w * hb1[(nb_ + 3) * 2560]; }

__global__ __launch_bounds__(256, 2) void x1_kernel(
    const float* __restrict__ pos, const float* __restrict__ h,
    const float* __restrict__ bw1, const float* __restrict__ bb1,
    const float* __restrict__ bb2,
    const unsigned short* __restrict__ wtb,   // bw2^T f16 [c][k]
    const unsigned short* __restrict__ wtk,   // kernel_w[l]^T f16 [c][k]
    float* __restrict__ x1)
{
    __shared__ __align__(16) unsigned short s_act[160 * SAS];  // 43520 B
    __shared__ float s_bw1[9 * SW];                            // folded monomial weights
    __shared__ float s_bb1[CDIM];

    const int tid = threadIdx.x;
    const int rg = tid & 15;
    const int cgv = tid >> 4;
    const int c0u = cgv << 3;

    // fold 14 poly rows -> 9 monomials: {3,4}->ab, {7,8,10}->a2b, {9,11,12}->ab2
    if (tid < CDIM) {
        const int c = tid;
        s_bw1[0 * SW + c] = bw1[0 * CDIM + c];
        s_bw1[1 * SW + c] = bw1[1 * CDIM + c];
        s_bw1[2 * SW + c] = bw1[2 * CDIM + c];
        s_bw1[3 * SW + c] = bw1[3 * CDIM + c] + bw1[4 * CDIM + c];
        s_bw1[4 * SW + c] = bw1[5 * CDIM + c];
        s_bw1[5 * SW + c] = bw1[6 * CDIM + c];
        s_bw1[6 * SW + c] = bw1[7 * CDIM + c] + bw1[8 * CDIM + c] + bw1[10 * CDIM + c];
        s_bw1[7 * SW + c] = bw1[9 * CDIM + c] + bw1[11 * CDIM + c] + bw1[12 * CDIM + c];
        s_bw1[8 * SW + c] = bw1[13 * CDIM + c];
        s_bb1[c] = bb1[c];
    }

    const int m = blockIdx.x / NORI;
    const int o = blockIdx.x % NORI;
    const float th = TWO_PI_OVER_O * (float)o;
    const float ox = cosf(th), oy = sinf(th);
    const float pmx = pos[2 * m], pmy = pos[2 * m + 1];

    __syncthreads();

    // ---- u-phase (fp32 VALU): u = gelu(monomials @ bw1f + bb1) -> f16 LDS (u/256)
#pragma unroll
    for (int rr = 0; rr < 10; ++rr) {
        const int row = rr * 16 + rg;
        float rx = pos[2 * row] - pmx, ry = pos[2 * row + 1] - pmy;
        float ia = rx * ox + ry * oy;
        float ib = sqrtf(rx * rx + ry * ry) * fabsf(1.0f - ia);
        float q2a = ia * ia, q2m = ia * ib, q2b = ib * ib;
        float q3a = q2a * ia, q3m = q2a * ib, q3n = q2m * ib, q3b = q2b * ib;
        float4 ua = ld4(&s_bb1[c0u]);
        float4 ub = ld4(&s_bb1[c0u + 4]);
#define UF(I, S) { float4 wa_ = ld4(&s_bw1[(I) * SW + c0u]); \
                   float4 wb_ = ld4(&s_bw1[(I) * SW + c0u + 4]); \
                   FMA4(ua, S, wa_); FMA4(ub, S, wb_); }
        UF(0, ia) UF(1, ib) UF(2, q2a) UF(3, q2m) UF(4, q2b)
        UF(5, q3a) UF(6, q3m) UF(7, q3n) UF(8, q3b)
#undef UF
        GELU4(ua) GELU4(ub)
        uint4 up;
        up.x = (unsigned int)f16b(ua.x * ISCL) | ((unsigned int)f16b(ua.y * ISCL) << 16);
        up.y = (unsigned int)f16b(ua.z * ISCL) | ((unsigned int)f16b(ua.w * ISCL) << 16);
        up.z = (unsigned int)f16b(ub.x * ISCL) | ((unsigned int)f16b(ub.y * ISCL) << 16);
        up.w = (unsigned int)f16b(ub.z * ISCL) | ((unsigned int)f16b(ub.w * ISCL) << 16);
        *(uint4*)&s_act[row * SAS + c0u] = up;
    }

    // ---- MFMA setup
    const int lane = tid & 63;
    const int wv = tid >> 6;          // wave id: col-tiles {2wv, 2wv+1}
    const int li = lane & 15;
    const int lh = lane >> 4;
    const int lh8 = lh << 3, lh4 = lh << 2;
    const int col0 = wv * 32 + li;
    const int col1 = col0 + 16;
    const int abase = li * SAS + lh8;
    const float4v vzero = {0.f, 0.f, 0.f, 0.f};

    FOR_BANDS(DECL_ACC)
    LOADB(bwf, wtb)                    // B-frags for GEMM1, in flight over barrier
    __syncthreads();                   // u visible

    FOR_BANDS(G1)                      // acc1 = (u/256) @ bw2
    __syncthreads();                   // all A-reads of u done

    const float zb0 = bb2[col0], zb1 = bb2[col1];
    FOR_BANDS(ZW_BAND)                 // z = gelu(256*acc1 + bb2); store z/256
    LOADB(kwf, wtk)                    // B-frags for GEMM2
    __syncthreads();                   // z visible

    FOR_BANDS(G2)                      // acc2 = (z/256) @ kw = kern/256

    // ---- x1 partial: 256 * sum_n acc2[n][c] * h[n,o,c]
    const float* hb0 = h + o * CDIM + col0;
    const float* hb1 = h + o * CDIM + col1;
    float xacc0 = 0.f, xacc1 = 0.f;
    FOR_BANDS(H_BAND)

    xacc0 += __shfl_xor(xacc0, 16, 64);
    xacc0 += __shfl_xor(xacc0, 32, 64);
    xacc1 += __shfl_xor(xacc1, 16, 64);
    xacc1 += __shfl_xor(xacc1, 32, 64);

    if (lane < 16) {
        float* x1p = x1 + (m * NORI + o) * CDIM;
        x1p[col0] = xacc0 * SCL;
        x1p[col1] = xacc1 * SCL;
    }
}

// ---------------------------------------------------------------------------
// fiber conv + LN + MLP + residual: 4 p-rows per block, grid = 160*5
// ---------------------------------------------------------------------------
__global__ __launch_bounds__(128) void mlp_kernel(
    const float* __restrict__ x1, const unsigned short* __restrict__ fk_l,
    const float* __restrict__ conv_b, const float* __restrict__ ln_g,
    const float* __restrict__ ln_b,
    const float* __restrict__ w1, const float* __restrict__ b1,
    const float* __restrict__ w2, const float* __restrict__ b2,
    float* __restrict__ h)
{
    __shared__ float s_xn[4][132];
    __shared__ float s_mid[4][520];
    __shared__ float s_s1[4][2], s_sq[4][2];

    const int c = threadIdx.x;
    const int m = blockIdx.x / 5, pg = blockIdx.x % 5;
    const int lane = c & 63, wid = c >> 6;

    float x1v[NORI];
#pragma unroll
    for (int o = 0; o < NORI; ++o) x1v[o] = x1[(m * NORI + o) * CDIM + c];

    float x2v[4];
#pragma unroll
    for (int rr = 0; rr < 4; ++rr) {
        int p = pg * 4 + rr;
        float x2 = 0.f;
#pragma unroll
        for (int o = 0; o < NORI; ++o) x2 += x1v[o] * f16tof(fk_l[(p * NORI + o) * CDIM + c]);
        x2 = x2 * (1.0f / 128.0f) + conv_b[c];
        x2v[rr] = x2;
        float s1 = x2, sq = x2 * x2;
        for (int off = 32; off; off >>= 1) {
            s1 += __shfl_down(s1, off, 64);
            sq += __shfl_down(sq, off, 64);
        }
        if (lane == 0) { s_s1[rr][wid] = s1; s_sq[rr][wid] = sq; }
    }
    __syncthreads();
#pragma unroll
    for (int rr = 0; rr < 4; ++rr) {
        float mu  = (s_s1[rr][0] + s_s1[rr][1]) * (1.0f / 128.0f);
        float var = (s_sq[rr][0] + s_sq[rr][1]) * (1.0f / 128.0f) - mu * mu;
        float xn = (x2v[rr] - mu) * rsqrtf(var + 1e-5f) * ln_g[c] + ln_b[c];
        s_xn[rr][c] = xn;
    }
    __syncthreads();

#pragma unroll
    for (int kq = 0; kq < 4; ++kq) {
        int k = kq * CDIM + c;
        float b = b1[k];
        float ac0 = b, ac1 = b, ac2 = b, ac3 = b;
        for (int i = 0; i < CDIM; ++i) {
            float w = w1[i * 512 + k];
            ac0 += s_xn[0][i] * w;
            ac1 += s_xn[1][i] * w;
            ac2 += s_xn[2][i] * w;
            ac3 += s_xn[3][i] * w;
        }
        s_mid[0][k] = gelu_exact(ac0);
        s_mid[1][k] = gelu_exact(ac1);
        s_mid[2][k] = gelu_exact(ac2);
        s_mid[3][k] = gelu_exact(ac3);
    }
    __syncthreads();

    float ao0 = 0.f, ao1 = 0.f, ao2 = 0.f, ao3 = 0.f;
    for (int k = 0; k < 512; ++k) {
        float w = w2[k * CDIM + c];
        ao0 += s_mid[0][k] * w;
        ao1 += s_mid[1][k] * w;
        ao2 += s_mid[2][k] * w;
        ao3 += s_mid[3][k] * w;
    }
    float bb = b2[c];
    h[(m * NORI + pg * 4 + 0) * CDIM + c] += ao0 + bb;
    h[(m * NORI + pg * 4 + 1) * CDIM + c] += ao1 + bb;
    h[(m * NORI + pg * 4 + 2) * CDIM + c] += ao2 + bb;
    h[(m * NORI + pg * 4 + 3) * CDIM + c] += ao3 + bb;
}

// ---------------------------------------------------------------------------
extern "C" void kernel_launch(void* const* d_in, const int* in_sizes, int n_in,
                              void* d_out, int out_size, void* d_ws, size_t ws_size,
                              hipStream_t stream)
{
    const float* x        = (const float*)d_in[0];
    const float* pos      = (const float*)d_in[1];
    const float* bw1      = (const float*)d_in[2];
    const float* bb1      = (const float*)d_in[3];
    const float* bw2      = (const float*)d_in[4];
    const float* bb2      = (const float*)d_in[5];
    const float* fw1      = (const float*)d_in[6];
    const float* fb1      = (const float*)d_in[7];
    const float* fw2      = (const float*)d_in[8];
    const float* fb2      = (const float*)d_in[9];
    const float* emb_w    = (const float*)d_in[10];
    const float* kernel_w = (const float*)d_in[11];
    const float* fiber_w  = (const float*)d_in[12];
    const float* conv_b   = (const float*)d_in[13];
    const float* ln_g     = (const float*)d_in[14];
    const float* ln_b     = (const float*)d_in[15];
    const float* mlp_w1   = (const float*)d_in[16];
    const float* mlp_b1   = (const float*)d_in[17];
    const float* mlp_w2   = (const float*)d_in[18];
    const float* mlp_b2   = (const float*)d_in[19];

    float* h = (float*)d_out;                       // [160,20,128]

    // ws layout (total 1,941,504 B, inside the r5-proven [0, 2,048,000 B)):
    unsigned short* wt = (unsigned short*)d_ws;     // [3][128][128] f16 = 98,304 B
    unsigned short* fk = wt + 3 * CDIM * CDIM;      // [2,20,20,128] f16 = 204,800 B
    float* x1 = (float*)(fk + 2 * NORI * NORI * CDIM);  // [160,20,128] f32 = 1,638,400 B

    wt_kernel<<<3 * CDIM, 128, 0, stream>>>(bw2, kernel_w, wt);
    fk_kernel<<<2 * NORI * NORI, 128, 0, stream>>>(fw1, fb1, fw2, fb2, fiber_w, fk);
    h0_kernel<<<NPTS * NORI, 128, 0, stream>>>(x, emb_w, h);

    for (int l = 0; l < 2; ++l) {
        x1_kernel<<<NPTS * NORI, 256, 0, stream>>>(
            pos, h, bw1, bb1, bb2, wt, wt + (1 + l) * CDIM * CDIM, x1);
        mlp_kernel<<<NPTS * NORI / 4, 128, 0, stream>>>(
            x1, fk + l * NORI * NORI * CDIM,
            conv_b + l * CDIM, ln_g + l * CDIM, ln_b + l * CDIM,
            mlp_w1 + l * CDIM * 4 * CDIM, mlp_b1 + l * 4 * CDIM,
            mlp_w2 + l * 4 * CDIM * CDIM, mlp_b2 + l * CDIM, h);
    }
}

// Round 10
// 318.148 us; speedup vs baseline: 23.6739x; 1.6068x over previous
//
#include <hip/hip_runtime.h>
#include <math.h>

#define NORI 20
#define NPTS 160
#define CDIM 128
#define TWO_PI_OVER_O (6.28318530717958647692f / 20.0f)
#define SW 132           // fp32 LDS row stride (s_bw1)
#define SAS 136          // s_act row stride in ushorts (f16), 272 B
#define SCL 256.0f       // activation storage scale (exact pow2)
#define ISCL 0.00390625f // 1/256

typedef __attribute__((ext_vector_type(8))) _Float16 half8v;
typedef __attribute__((ext_vector_type(4))) float float4v;

// Fast exact-GELU: erf via Abramowitz-Stegun 7.1.26 (|err| < 1.5e-7).
// ~15 VALU ops (v_rcp_f32 + v_exp_f32 are single HW instructions) vs
// ~90 for ocml erff — r9 PMC showed 160 erff/thread = ~14K of ~17K inst.
__device__ __forceinline__ float gelu_exact(float x) {
    float t  = 0.70710678118654752440f * x;
    float at = fabsf(t);
    float tau = __builtin_amdgcn_rcpf(fmaf(0.3275911f, at, 1.0f));
    float p = fmaf(1.061405429f, tau, -1.453152027f);
    p = fmaf(p, tau, 1.421413741f);
    p = fmaf(p, tau, -0.284496736f);
    p = fmaf(p, tau, 0.254829592f);
    p = p * tau;
    float e = __expf(-t * t);                 // v_exp_f32 path
    float erf_abs = fmaf(-p, e, 1.0f);
    float erf_t = copysignf(erf_abs, t);
    return 0.5f * x * (1.0f + erf_t);
}
__device__ __forceinline__ float4 ld4(const float* p) { return *(const float4*)p; }
__device__ __forceinline__ unsigned short f16b(float f) {
    _Float16 h = (_Float16)f;                 // RNE convert
    return __builtin_bit_cast(unsigned short, h);
}
__device__ __forceinline__ float f16tof(unsigned short u) {
    return (float)__builtin_bit_cast(_Float16, u);
}

#define FMA4(d, s, v) { d.x += (s)*(v).x; d.y += (s)*(v).y; d.z += (s)*(v).z; d.w += (s)*(v).w; }
#define GELU4(d) { d.x = gelu_exact(d.x); d.y = gelu_exact(d.y); \
                   d.z = gelu_exact(d.z); d.w = gelu_exact(d.w); }

// ---------------------------------------------------------------------------
// fk[l,p,o,c]  (stored f16; |fk| ~ O(10) well within f16 range)
// ---------------------------------------------------------------------------
__global__ __launch_bounds__(128) void fk_kernel(
    const float* __restrict__ fw1, const float* __restrict__ fb1,
    const float* __restrict__ fw2, const float* __restrict__ fb2,
    const float* __restrict__ fiber_w, unsigned short* __restrict__ fk)
{
    __shared__ float s_u[CDIM];
    __shared__ float s_z[CDIM];
    int bid = blockIdx.x;
    int l = bid / 400;
    int rem = bid % 400;
    int p = rem / 20, o = rem % 20;
    int j = threadIdx.x;

    float t = cosf(TWO_PI_OVER_O * (float)(p - o));
    float f1 = t * t, f2 = f1 * t;

    float u = gelu_exact(t * fw1[j] + f1 * fw1[CDIM + j] + f2 * fw1[2 * CDIM + j] + fb1[j]);
    s_u[j] = u;
    __syncthreads();

    float z0 = 0.f, z1 = 0.f, z2 = 0.f, z3 = 0.f;
    for (int i = 0; i < CDIM; i += 4) {
        z0 += s_u[i    ] * fw2[(i    ) * CDIM + j];
        z1 += s_u[i + 1] * fw2[(i + 1) * CDIM + j];
        z2 += s_u[i + 2] * fw2[(i + 2) * CDIM + j];
        z3 += s_u[i + 3] * fw2[(i + 3) * CDIM + j];
    }
    float z = gelu_exact(((z0 + z1) + (z2 + z3)) + fb2[j]);
    s_z[j] = z;
    __syncthreads();

    const float* fw = fiber_w + l * CDIM * CDIM;
    float a0 = 0.f, a1 = 0.f, a2 = 0.f, a3 = 0.f;
    for (int i = 0; i < CDIM; i += 4) {
        a0 += s_z[i    ] * fw[(i    ) * CDIM + j];
        a1 += s_z[i + 1] * fw[(i + 1) * CDIM + j];
        a2 += s_z[i + 2] * fw[(i + 2) * CDIM + j];
        a3 += s_z[i + 3] * fw[(i + 3) * CDIM + j];
    }
    fk[bid * CDIM + j] = f16b((a0 + a1) + (a2 + a3));
}

// ---------------------------------------------------------------------------
// h0
// ---------------------------------------------------------------------------
__global__ __launch_bounds__(128) void h0_kernel(
    const float* __restrict__ x, const float* __restrict__ emb_w,
    float* __restrict__ h)
{
    int row = blockIdx.x;
    int j = threadIdx.x;
    const float* xr = x + row * 16;
    float acc = 0.f;
#pragma unroll
    for (int i = 0; i < 16; ++i) acc += xr[i] * emb_w[i * CDIM + j];
    h[row * CDIM + j] = acc;
}

// ---------------------------------------------------------------------------
// wt: f16 transposed weights wt[mat][c][k] = f16(w[k][c]); |w| ≤ ~1 — safe
// ---------------------------------------------------------------------------
__global__ __launch_bounds__(128) void wt_kernel(
    const float* __restrict__ bw2, const float* __restrict__ kernel_w,
    unsigned short* __restrict__ wt)
{
    int b = blockIdx.x;            // mat*128 + c
    int mat = b >> 7, c = b & 127;
    const float* src = (mat == 0) ? bw2 : (kernel_w + (mat - 1) * CDIM * CDIM);
    int k = threadIdx.x;
    wt[(mat * CDIM + c) * CDIM + k] = f16b(src[k * CDIM + c]);
}

// ---------------------------------------------------------------------------
// x1 kernel — MFMA path (fp16 operands SCALED by 1/256, fp32 accum).
// mfma 16x16x32 layouts (shape-determined, dtype-independent):
// A: row=lane&15, k=(lane>>4)*8+e;  B: col=lane&15, k=(lane>>4)*8+e;
// C/D: col=lane&15, row=(lane>>4)*4+reg  [m89-verified].
// ---------------------------------------------------------------------------
#define FOR_BANDS(X) X(0) X(1) X(2) X(3) X(4) X(5) X(6) X(7) X(8) X(9)

#define DECL_ACC(B) float4v acc##B##_0 = {0.f,0.f,0.f,0.f}, acc##B##_1 = {0.f,0.f,0.f,0.f};

#define LDB(PTR, COL, KT) (*(const half8v*)((PTR) + (COL) * CDIM + (KT) * 32 + lh8))

#define LOADB(P, PTR) \
    half8v P##0_0 = LDB(PTR, col0, 0), P##0_1 = LDB(PTR, col1, 0); \
    half8v P##1_0 = LDB(PTR, col0, 1), P##1_1 = LDB(PTR, col1, 1); \
    half8v P##2_0 = LDB(PTR, col0, 2), P##2_1 = LDB(PTR, col1, 2); \
    half8v P##3_0 = LDB(PTR, col0, 3), P##3_1 = LDB(PTR, col1, 3);

#define G_BAND(B, P) { \
    const unsigned short* ar_ = s_act + (B) * 16 * SAS + abase; \
    half8v a0_ = *(const half8v*)(ar_); \
    half8v a1_ = *(const half8v*)(ar_ + 32); \
    half8v a2_ = *(const half8v*)(ar_ + 64); \
    half8v a3_ = *(const half8v*)(ar_ + 96); \
    acc##B##_0 = __builtin_amdgcn_mfma_f32_16x16x32_f16(a0_, P##0_0, acc##B##_0, 0, 0, 0); \
    acc##B##_1 = __builtin_amdgcn_mfma_f32_16x16x32_f16(a0_, P##0_1, acc##B##_1, 0, 0, 0); \
    acc##B##_0 = __builtin_amdgcn_mfma_f32_16x16x32_f16(a1_, P##1_0, acc##B##_0, 0, 0, 0); \
    acc##B##_1 = __builtin_amdgcn_mfma_f32_16x16x32_f16(a1_, P##1_1, acc##B##_1, 0, 0, 0); \
    acc##B##_0 = __builtin_amdgcn_mfma_f32_16x16x32_f16(a2_, P##2_0, acc##B##_0, 0, 0, 0); \
    acc##B##_1 = __builtin_amdgcn_mfma_f32_16x16x32_f16(a2_, P##2_1, acc##B##_1, 0, 0, 0); \
    acc##B##_0 = __builtin_amdgcn_mfma_f32_16x16x32_f16(a3_, P##3_0, acc##B##_0, 0, 0, 0); \
    acc##B##_1 = __builtin_amdgcn_mfma_f32_16x16x32_f16(a3_, P##3_1, acc##B##_1, 0, 0, 0); }

#define G1(B) G_BAND(B, bwf)
#define G2(B) G_BAND(B, kwf)

// z = gelu(256*acc + bb2), store z/256 as f16
#define ZW_BAND(B) { \
    int rb_ = (B) * 16 + lh4; \
    s_act[(rb_ + 0) * SAS + col0] = f16b(gelu_exact(fmaf(SCL, acc##B##_0.x, zb0)) * ISCL); \
    s_act[(rb_ + 1) * SAS + col0] = f16b(gelu_exact(fmaf(SCL, acc##B##_0.y, zb0)) * ISCL); \
    s_act[(rb_ + 2) * SAS + col0] = f16b(gelu_exact(fmaf(SCL, acc##B##_0.z, zb0)) * ISCL); \
    s_act[(rb_ + 3) * SAS + col0] = f16b(gelu_exact(fmaf(SCL, acc##B##_0.w, zb0)) * ISCL); \
    s_act[(rb_ + 0) * SAS + col1] = f16b(gelu_exact(fmaf(SCL, acc##B##_1.x, zb1)) * ISCL); \
    s_act[(rb_ + 1) * SAS + col1] = f16b(gelu_exact(fmaf(SCL, acc##B##_1.y, zb1)) * ISCL); \
    s_act[(rb_ + 2) * SAS + col1] = f16b(gelu_exact(fmaf(SCL, acc##B##_1.z, zb1)) * ISCL); \
    s_act[(rb_ + 3) * SAS + col1] = f16b(gelu_exact(fmaf(SCL, acc##B##_1.w, zb1)) * ISCL); \
    acc##B##_0 = vzero; acc##B##_1 = vzero; }

#define H_BAND(B) { \
    int nb_ = (B) * 16 + lh4; \
    xacc0 += acc##B##_0.x * hb0[(nb_ + 0) * 2560]; \
    xacc0 += acc##B##_0.y * hb0[(nb_ + 1) * 2560]; \
    xacc0 += acc##B##_0.z * hb0[(nb_ + 2) * 2560]; \
    xacc0 += acc##B##_0.w * hb0[(nb_ + 3) * 2560]; \
    xacc1 += acc##B##_1.x * hb1[(nb_ + 0) * 2560]; \
    xacc1 += acc##B##_1.y * hb1[(nb_ + 1) * 2560]; \
    xacc1 += acc##B##_1.z * hb1[(nb_ + 2) * 2560]; \
    xacc1 += acc##B##_1.w * hb1[(nb_ + 3) * 2560]; }

__global__ __launch_bounds__(256, 2) void x1_kernel(
    const float* __restrict__ pos, const float* __restrict__ h,
    const float* __restrict__ bw1, const float* __restrict__ bb1,
    const float* __restrict__ bb2,
    const unsigned short* __restrict__ wtb,   // bw2^T f16 [c][k]
    const unsigned short* __restrict__ wtk,   // kernel_w[l]^T f16 [c][k]
    float* __restrict__ x1)
{
    __shared__ __align__(16) unsigned short s_act[160 * SAS];  // 43520 B
    __shared__ float s_bw1[9 * SW];                            // folded monomial weights
    __shared__ float s_bb1[CDIM];

    const int tid = threadIdx.x;
    const int rg = tid & 15;
    const int cgv = tid >> 4;
    const int c0u = cgv << 3;

    // fold 14 poly rows -> 9 monomials: {3,4}->ab, {7,8,10}->a2b, {9,11,12}->ab2
    if (tid < CDIM) {
        const int c = tid;
        s_bw1[0 * SW + c] = bw1[0 * CDIM + c];
        s_bw1[1 * SW + c] = bw1[1 * CDIM + c];
        s_bw1[2 * SW + c] = bw1[2 * CDIM + c];
        s_bw1[3 * SW + c] = bw1[3 * CDIM + c] + bw1[4 * CDIM + c];
        s_bw1[4 * SW + c] = bw1[5 * CDIM + c];
        s_bw1[5 * SW + c] = bw1[6 * CDIM + c];
        s_bw1[6 * SW + c] = bw1[7 * CDIM + c] + bw1[8 * CDIM + c] + bw1[10 * CDIM + c];
        s_bw1[7 * SW + c] = bw1[9 * CDIM + c] + bw1[11 * CDIM + c] + bw1[12 * CDIM + c];
        s_bw1[8 * SW + c] = bw1[13 * CDIM + c];
        s_bb1[c] = bb1[c];
    }

    const int m = blockIdx.x / NORI;
    const int o = blockIdx.x % NORI;
    const float th = TWO_PI_OVER_O * (float)o;
    const float ox = cosf(th), oy = sinf(th);
    const float pmx = pos[2 * m], pmy = pos[2 * m + 1];

    __syncthreads();

    // ---- u-phase (fp32 VALU): u = gelu(monomials @ bw1f + bb1) -> f16 LDS (u/256)
#pragma unroll
    for (int rr = 0; rr < 10; ++rr) {
        const int row = rr * 16 + rg;
        float rx = pos[2 * row] - pmx, ry = pos[2 * row + 1] - pmy;
        float ia = rx * ox + ry * oy;
        float ib = sqrtf(rx * rx + ry * ry) * fabsf(1.0f - ia);
        float q2a = ia * ia, q2m = ia * ib, q2b = ib * ib;
        float q3a = q2a * ia, q3m = q2a * ib, q3n = q2m * ib, q3b = q2b * ib;
        float4 ua = ld4(&s_bb1[c0u]);
        float4 ub = ld4(&s_bb1[c0u + 4]);
#define UF(I, S) { float4 wa_ = ld4(&s_bw1[(I) * SW + c0u]); \
                   float4 wb_ = ld4(&s_bw1[(I) * SW + c0u + 4]); \
                   FMA4(ua, S, wa_); FMA4(ub, S, wb_); }
        UF(0, ia) UF(1, ib) UF(2, q2a) UF(3, q2m) UF(4, q2b)
        UF(5, q3a) UF(6, q3m) UF(7, q3n) UF(8, q3b)
#undef UF
        GELU4(ua) GELU4(ub)
        uint4 up;
        up.x = (unsigned int)f16b(ua.x * ISCL) | ((unsigned int)f16b(ua.y * ISCL) << 16);
        up.y = (unsigned int)f16b(ua.z * ISCL) | ((unsigned int)f16b(ua.w * ISCL) << 16);
        up.z = (unsigned int)f16b(ub.x * ISCL) | ((unsigned int)f16b(ub.y * ISCL) << 16);
        up.w = (unsigned int)f16b(ub.z * ISCL) | ((unsigned int)f16b(ub.w * ISCL) << 16);
        *(uint4*)&s_act[row * SAS + c0u] = up;
    }

    // ---- MFMA setup
    const int lane = tid & 63;
    const int wv = tid >> 6;          // wave id: col-tiles {2wv, 2wv+1}
    const int li = lane & 15;
    const int lh = lane >> 4;
    const int lh8 = lh << 3, lh4 = lh << 2;
    const int col0 = wv * 32 + li;
    const int col1 = col0 + 16;
    const int abase = li * SAS + lh8;
    const float4v vzero = {0.f, 0.f, 0.f, 0.f};

    FOR_BANDS(DECL_ACC)
    LOADB(bwf, wtb)                    // B-frags for GEMM1, in flight over barrier
    __syncthreads();                   // u visible

    FOR_BANDS(G1)                      // acc1 = (u/256) @ bw2
    __syncthreads();                   // all A-reads of u done

    const float zb0 = bb2[col0], zb1 = bb2[col1];
    FOR_BANDS(ZW_BAND)                 // z = gelu(256*acc1 + bb2); store z/256
    LOADB(kwf, wtk)                    // B-frags for GEMM2
    __syncthreads();                   // z visible

    FOR_BANDS(G2)                      // acc2 = (z/256) @ kw = kern/256

    // ---- x1 partial: 256 * sum_n acc2[n][c] * h[n,o,c]
    const float* hb0 = h + o * CDIM + col0;
    const float* hb1 = h + o * CDIM + col1;
    float xacc0 = 0.f, xacc1 = 0.f;
    FOR_BANDS(H_BAND)

    xacc0 += __shfl_xor(xacc0, 16, 64);
    xacc0 += __shfl_xor(xacc0, 32, 64);
    xacc1 += __shfl_xor(xacc1, 16, 64);
    xacc1 += __shfl_xor(xacc1, 32, 64);

    if (lane < 16) {
        float* x1p = x1 + (m * NORI + o) * CDIM;
        x1p[col0] = xacc0 * SCL;
        x1p[col1] = xacc1 * SCL;
    }
}

// ---------------------------------------------------------------------------
// fiber conv + LN + MLP + residual: 4 p-rows per block, grid = 160*5
// ---------------------------------------------------------------------------
__global__ __launch_bounds__(128) void mlp_kernel(
    const float* __restrict__ x1, const unsigned short* __restrict__ fk_l,
    const float* __restrict__ conv_b, const float* __restrict__ ln_g,
    const float* __restrict__ ln_b,
    const float* __restrict__ w1, const float* __restrict__ b1,
    const float* __restrict__ w2, const float* __restrict__ b2,
    float* __restrict__ h)
{
    __shared__ float s_xn[4][132];
    __shared__ float s_mid[4][520];
    __shared__ float s_s1[4][2], s_sq[4][2];

    const int c = threadIdx.x;
    const int m = blockIdx.x / 5, pg = blockIdx.x % 5;
    const int lane = c & 63, wid = c >> 6;

    float x1v[NORI];
#pragma unroll
    for (int o = 0; o < NORI; ++o) x1v[o] = x1[(m * NORI + o) * CDIM + c];

    float x2v[4];
#pragma unroll
    for (int rr = 0; rr < 4; ++rr) {
        int p = pg * 4 + rr;
        float x2 = 0.f;
#pragma unroll
        for (int o = 0; o < NORI; ++o) x2 += x1v[o] * f16tof(fk_l[(p * NORI + o) * CDIM + c]);
        x2 = x2 * (1.0f / 128.0f) + conv_b[c];
        x2v[rr] = x2;
        float s1 = x2, sq = x2 * x2;
        for (int off = 32; off; off >>= 1) {
            s1 += __shfl_down(s1, off, 64);
            sq += __shfl_down(sq, off, 64);
        }
        if (lane == 0) { s_s1[rr][wid] = s1; s_sq[rr][wid] = sq; }
    }
    __syncthreads();
#pragma unroll
    for (int rr = 0; rr < 4; ++rr) {
        float mu  = (s_s1[rr][0] + s_s1[rr][1]) * (1.0f / 128.0f);
        float var = (s_sq[rr][0] + s_sq[rr][1]) * (1.0f / 128.0f) - mu * mu;
        float xn = (x2v[rr] - mu) * rsqrtf(var + 1e-5f) * ln_g[c] + ln_b[c];
        s_xn[rr][c] = xn;
    }
    __syncthreads();

#pragma unroll
    for (int kq = 0; kq < 4; ++kq) {
        int k = kq * CDIM + c;
        float b = b1[k];
        float ac0 = b, ac1 = b, ac2 = b, ac3 = b;
        for (int i = 0; i < CDIM; ++i) {
            float w = w1[i * 512 + k];
            ac0 += s_xn[0][i] * w;
            ac1 += s_xn[1][i] * w;
            ac2 += s_xn[2][i] * w;
            ac3 += s_xn[3][i] * w;
        }
        s_mid[0][k] = gelu_exact(ac0);
        s_mid[1][k] = gelu_exact(ac1);
        s_mid[2][k] = gelu_exact(ac2);
        s_mid[3][k] = gelu_exact(ac3);
    }
    __syncthreads();

    float ao0 = 0.f, ao1 = 0.f, ao2 = 0.f, ao3 = 0.f;
    for (int k = 0; k < 512; ++k) {
        float w = w2[k * CDIM + c];
        ao0 += s_mid[0][k] * w;
        ao1 += s_mid[1][k] * w;
        ao2 += s_mid[2][k] * w;
        ao3 += s_mid[3][k] * w;
    }
    float bb = b2[c];
    h[(m * NORI + pg * 4 + 0) * CDIM + c] += ao0 + bb;
    h[(m * NORI + pg * 4 + 1) * CDIM + c] += ao1 + bb;
    h[(m * NORI + pg * 4 + 2) * CDIM + c] += ao2 + bb;
    h[(m * NORI + pg * 4 + 3) * CDIM + c] += ao3 + bb;
}

// ---------------------------------------------------------------------------
extern "C" void kernel_launch(void* const* d_in, const int* in_sizes, int n_in,
                              void* d_out, int out_size, void* d_ws, size_t ws_size,
                              hipStream_t stream)
{
    const float* x        = (const float*)d_in[0];
    const float* pos      = (const float*)d_in[1];
    const float* bw1      = (const float*)d_in[2];
    const float* bb1      = (const float*)d_in[3];
    const float* bw2      = (const float*)d_in[4];
    const float* bb2      = (const float*)d_in[5];
    const float* fw1      = (const float*)d_in[6];
    const float* fb1      = (const float*)d_in[7];
    const float* fw2      = (const float*)d_in[8];
    const float* fb2      = (const float*)d_in[9];
    const float* emb_w    = (const float*)d_in[10];
    const float* kernel_w = (const float*)d_in[11];
    const float* fiber_w  = (const float*)d_in[12];
    const float* conv_b   = (const float*)d_in[13];
    const float* ln_g     = (const float*)d_in[14];
    const float* ln_b     = (const float*)d_in[15];
    const float* mlp_w1   = (const float*)d_in[16];
    const float* mlp_b1   = (const float*)d_in[17];
    const float* mlp_w2   = (const float*)d_in[18];
    const float* mlp_b2   = (const float*)d_in[19];

    float* h = (float*)d_out;                       // [160,20,128]

    // ws layout (total 1,941,504 B, inside the r5-proven [0, 2,048,000 B)):
    unsigned short* wt = (unsigned short*)d_ws;     // [3][128][128] f16 = 98,304 B
    unsigned short* fk = wt + 3 * CDIM * CDIM;      // [2,20,20,128] f16 = 204,800 B
    float* x1 = (float*)(fk + 2 * NORI * NORI * CDIM);  // [160,20,128] f32 = 1,638,400 B

    wt_kernel<<<3 * CDIM, 128, 0, stream>>>(bw2, kernel_w, wt);
    fk_kernel<<<2 * NORI * NORI, 128, 0, stream>>>(fw1, fb1, fw2, fb2, fiber_w, fk);
    h0_kernel<<<NPTS * NORI, 128, 0, stream>>>(x, emb_w, h);

    for (int l = 0; l < 2; ++l) {
        x1_kernel<<<NPTS * NORI, 256, 0, stream>>>(
            pos, h, bw1, bb1, bb2, wt, wt + (1 + l) * CDIM * CDIM, x1);
        mlp_kernel<<<NPTS * NORI / 4, 128, 0, stream>>>(
            x1, fk + l * NORI * NORI * CDIM,
            conv_b + l * CDIM, ln_g + l * CDIM, ln_b + l * CDIM,
            mlp_w1 + l * CDIM * 4 * CDIM, mlp_b1 + l * 4 * CDIM,
            mlp_w2 + l * 4 * CDIM * CDIM, mlp_b2 + l * CDIM, h);
    }
}